// Round 4
// baseline (2526.402 us; speedup 1.0000x reference)
//
#include <hip/hip_runtime.h>

#define NB 64
#define CB 64
#define TB 300
#define VB 25
#define SB 3
#define KB 9
#define LV 28            // padded V stride in LDS (112B rows, 16B aligned)
#define NCNTF 480000.0f  // N*T*V per channel

// ws float offsets
#define WS_SUM1 0
#define WS_SQ1  64
#define WS_SC1  128
#define WS_SH1  192
#define WS_SUM2 256
#define WS_SQ2  320
#define WS_SC2  384
#define WS_SH2  448
#define WS_WDT  512
#define WS_WTT  (512 + 3*64*64)
#define WS_AQ   (WS_WTT + 9*64*64)
#define WS_Z_BYTE 262144   // z (bf16) lives here: 30.72M * 2B = 61.44MB

__device__ __forceinline__ float bf2f(unsigned short u) {
  unsigned int v = ((unsigned int)u) << 16;
  float f; __builtin_memcpy(&f, &v, 4); return f;
}
__device__ __forceinline__ unsigned short f2bf(float f) {
  unsigned int x; __builtin_memcpy(&x, &f, 4);
  x += 0x7fffu + ((x >> 16) & 1u);
  return (unsigned short)(x >> 16);
}

// ---------------- K0: prep (quantize Aq, transposes, zero stats) ------------
__global__ void k0_prep(const float* __restrict__ A, const float* __restrict__ PA,
                        const float* __restrict__ Wd, const float* __restrict__ Wt,
                        float* __restrict__ ws) {
  int tid = threadIdx.x;
  for (int i = tid; i < 512; i += 256) ws[i] = 0.f;
  // WdT[s][c][o] = Wd[s][o][c]
  for (int i = tid; i < SB*CB*CB; i += 256) {
    int o = i & 63, c = (i >> 6) & 63, s = i >> 12;
    ws[WS_WDT + i] = Wd[(s*64 + o)*64 + c];
  }
  // WtT[k][i][o] = Wt[o][i][k]
  for (int i = tid; i < KB*CB*CB; i += 256) {
    int o = i & 63, ii = (i >> 6) & 63, k = i >> 12;
    ws[WS_WTT + i] = Wt[(o*64 + ii)*9 + k];
  }
  // Aq = clip(trunc((A+PA)*1024), -32768, 32768) / 1024
  for (int i = tid; i < SB*VB*VB; i += 256) {
    float a = A[i] + PA[i];
    float q = truncf(a * 1024.f);
    q = fminf(fmaxf(q, -32768.f), 32768.f);
    ws[WS_AQ + i] = q * (1.f/1024.f);
  }
}

// ---------------- K1: GCN  z = sum_s Wd[s] @ x @ Aq[s] + bias ---------------
__global__ __launch_bounds__(256) void k1_gcn(
    const float* __restrict__ x, const float* __restrict__ bd,
    const float* __restrict__ ws, float* __restrict__ wstat,
    unsigned short* __restrict__ zout)
{
  __shared__ float xls[CB][4][LV];          // 28672 B
  __shared__ float aqs[SB*VB*VB];           // 7500 B
  __shared__ float s_sum[CB], s_sq[CB];
  int tid = threadIdx.x;
  int t0 = blockIdx.x * 4;                  // 75 * 4 == 300 exact
  int n  = blockIdx.y;

  // stage x tile: one (c, tl) row of 25 floats per thread, zero-pad to 28
  {
    int c = tid >> 2, tl = tid & 3;
    int t = t0 + tl;
    const float* xr = x + (((size_t)n*CB + c)*TB + t)*VB;
    #pragma unroll
    for (int v = 0; v < LV; ++v)
      xls[c][tl][v] = (v < VB) ? xr[v] : 0.f;
  }
  for (int i = tid; i < SB*VB*VB; i += 256) aqs[i] = ws[WS_AQ + i];
  if (tid < CB) { s_sum[tid] = 0.f; s_sq[tid] = 0.f; }
  __syncthreads();

  int o  = tid & 63;       // output channel (lane-consecutive)
  int th = tid >> 6;       // timestep within chunk (wave-uniform)
  float zac[VB];
  #pragma unroll
  for (int w = 0; w < VB; ++w) zac[w] = 0.f;

  const float* wdt = ws + WS_WDT;
  for (int s = 0; s < SB; ++s) {
    // u[v] = sum_c WdT[s][c][o] * x[c][th][v]
    float u[VB];
    #pragma unroll
    for (int v = 0; v < VB; ++v) u[v] = 0.f;
    for (int c = 0; c < CB; ++c) {
      float wd = wdt[(s*CB + c)*CB + o];
      #pragma unroll
      for (int v = 0; v < VB; ++v)
        u[v] = fmaf(wd, xls[c][th][v], u[v]);
    }
    // zac[w] += sum_v u[v] * Aq[s][v][w]
    #pragma unroll
    for (int v = 0; v < VB; ++v) {
      const float* ar = &aqs[(s*VB + v)*VB];
      float uv = u[v];
      #pragma unroll
      for (int w = 0; w < VB; ++w)
        zac[w] = fmaf(uv, ar[w], zac[w]);
    }
  }

  int t = t0 + th;   // always < 300
  {
    float bsum = bd[o] + bd[CB + o] + bd[2*CB + o];
    unsigned short* zr = zout + (((size_t)n*CB + o)*TB + t)*VB;
    float sm = 0.f, sq = 0.f;
    #pragma unroll
    for (int w = 0; w < VB; ++w) {
      float zv = zac[w] + bsum;
      zr[w] = f2bf(zv);
      sm += zv; sq += zv*zv;
    }
    atomicAdd(&s_sum[o], sm);
    atomicAdd(&s_sq[o], sq);
  }
  __syncthreads();
  if (tid < CB) {
    atomicAdd(&wstat[WS_SUM1 + tid], s_sum[tid]);
    atomicAdd(&wstat[WS_SQ1  + tid], s_sq[tid]);
  }
}

// ---------------- K2/K4: fold BN stats into scale/shift ---------------------
__global__ void k_fin(const float* __restrict__ g, const float* __restrict__ b,
                      float* __restrict__ ws, int soff) {
  int c = threadIdx.x;
  float m   = ws[soff + c] * (1.f/NCNTF);
  float var = ws[soff + 64 + c] * (1.f/NCNTF) - m*m;
  float rstd = rsqrtf(var + 1e-5f);
  float sc = rstd * g[c];
  ws[soff + 128 + c] = sc;
  ws[soff + 192 + c] = b[c] - m * sc;
}

// ---------------- K3: y = relu(bn1(z)+x) on the fly; 9-tap temporal conv ----
__global__ __launch_bounds__(256) void k3_tconv(
    const float* __restrict__ x, const unsigned short* __restrict__ z,
    const float* __restrict__ bt, const float* __restrict__ ws,
    float* __restrict__ wstat, float* __restrict__ tcout)
{
  __shared__ float yls[16][16][LV];   // 16 channels, 8 outputs + 8 halo: 28672B
  __shared__ float s_sum[CB], s_sq[CB];
  int tid = threadIdx.x;
  int t0 = blockIdx.x * 8;
  int n  = blockIdx.y;
  int o4 = tid & 15;          // o = o4*4 + a
  int th = (tid >> 4) & 7;    // output timestep within chunk
  int vh = tid >> 7;          // v half
  int v0 = vh * 12;           // overlap col 12, masked at emit

  float acc0[13], acc1[13], acc2[13], acc3[13];
  #pragma unroll
  for (int b = 0; b < 13; ++b) { acc0[b]=0.f; acc1[b]=0.f; acc2[b]=0.f; acc3[b]=0.f; }
  if (tid < CB) { s_sum[tid] = 0.f; s_sq[tid] = 0.f; }

  const float* wtt = ws + WS_WTT;
  for (int ih = 0; ih < 4; ++ih) {
    __syncthreads();
    // stage y quarter-tile: one (ii, tl) row per thread; i in [ih*16, ih*16+16)
    {
      int ii = tid >> 4, tl = tid & 15;
      int i = ih*16 + ii;
      int t = t0 + tl - 4;
      bool ok = (t >= 0 && t < TB);
      float sc = ws[WS_SC1 + i], sh = ws[WS_SH1 + i];
      size_t base = (((size_t)n*CB + i)*TB + t)*VB;
      #pragma unroll
      for (int v = 0; v < LV; ++v) {
        float y = 0.f;
        if (ok && v < VB) {
          float zv = bf2f(z[base + v]);
          y = fmaxf(fmaf(zv, sc, sh) + x[base + v], 0.f);
        }
        yls[ii][tl][v] = y;
      }
    }
    __syncthreads();
    for (int k = 0; k < KB; ++k) {
      for (int i = 0; i < 16; ++i) {
        const float4 wt = *(const float4*)(wtt + ((k*CB + ih*16 + i)*CB) + o4*4);
        const float* yr = &yls[i][th + k][v0];
        #pragma unroll
        for (int b = 0; b < 13; ++b) {
          float yv = yr[b];
          acc0[b] = fmaf(wt.x, yv, acc0[b]);
          acc1[b] = fmaf(wt.y, yv, acc1[b]);
          acc2[b] = fmaf(wt.z, yv, acc2[b]);
          acc3[b] = fmaf(wt.w, yv, acc3[b]);
        }
      }
    }
  }

  int t = t0 + th;
  if (t < TB) {
#define EMITC(A_, ACC_) { \
    int o = o4*4 + (A_); \
    float bta = bt[o]; \
    float* tr = tcout + (((size_t)n*CB + o)*TB + t)*VB; \
    float sm = 0.f, sq = 0.f; \
    _Pragma("unroll") \
    for (int b = 0; b < 13; ++b) { \
      if (vh == 0 || b > 0) { \
        int v = v0 + b; \
        float val = ACC_[b] + bta; \
        tr[v] = val; sm += val; sq += val*val; } } \
    atomicAdd(&s_sum[o], sm); atomicAdd(&s_sq[o], sq); }
    EMITC(0, acc0) EMITC(1, acc1) EMITC(2, acc2) EMITC(3, acc3)
#undef EMITC
  }
  __syncthreads();
  if (tid < CB) {
    atomicAdd(&wstat[WS_SUM2 + tid], s_sum[tid]);
    atomicAdd(&wstat[WS_SQ2  + tid], s_sq[tid]);
  }
}

// ---------------- K5: out = relu(bn2(tc) + x), in-place on d_out (f32) ------
__global__ void k5_final(const float* __restrict__ x, const float* __restrict__ ws,
                         float* __restrict__ out) {
  int idx = blockIdx.x * blockDim.x + threadIdx.x;
  int stride = gridDim.x * blockDim.x;
  const int total4 = NB*CB*TB*VB/4;   // 7500 per (n,c) plane, /4 = 1875 exact
  for (int i = idx; i < total4; i += stride) {
    int c = (i / 1875) & 63;
    float sc = ws[WS_SC2 + c], sh = ws[WS_SH2 + c];
    float4 t4 = ((const float4*)out)[i];
    float4 x4 = ((const float4*)x)[i];
    float4 r;
    r.x = fmaxf(fmaf(t4.x, sc, sh) + x4.x, 0.f);
    r.y = fmaxf(fmaf(t4.y, sc, sh) + x4.y, 0.f);
    r.z = fmaxf(fmaf(t4.z, sc, sh) + x4.z, 0.f);
    r.w = fmaxf(fmaf(t4.w, sc, sh) + x4.w, 0.f);
    ((float4*)out)[i] = r;
  }
}

extern "C" void kernel_launch(void* const* d_in, const int* in_sizes, int n_in,
                              void* d_out, int out_size, void* d_ws, size_t ws_size,
                              hipStream_t stream) {
  const float* x  = (const float*)d_in[0];
  const float* A  = (const float*)d_in[1];
  const float* PA = (const float*)d_in[2];
  const float* Wd = (const float*)d_in[3];
  const float* bd = (const float*)d_in[4];
  const float* g1 = (const float*)d_in[5];
  const float* b1 = (const float*)d_in[6];
  const float* Wt = (const float*)d_in[7];
  const float* bt = (const float*)d_in[8];
  const float* g2 = (const float*)d_in[9];
  const float* b2 = (const float*)d_in[10];

  float* ws = (float*)d_ws;
  unsigned short* zbuf = (unsigned short*)((char*)d_ws + WS_Z_BYTE);
  float* out = (float*)d_out;

  k0_prep<<<dim3(1), dim3(256), 0, stream>>>(A, PA, Wd, Wt, ws);
  k1_gcn<<<dim3(75, 64), dim3(256), 0, stream>>>(x, bd, ws, ws, zbuf);
  k_fin<<<dim3(1), dim3(64), 0, stream>>>(g1, b1, ws, 0);
  k3_tconv<<<dim3(38, 64), dim3(256), 0, stream>>>(x, zbuf, bt, ws, ws, out);
  k_fin<<<dim3(1), dim3(64), 0, stream>>>(g2, b2, ws, 256);
  k5_final<<<dim3(2048), dim3(256), 0, stream>>>(x, ws, out);
}

// Round 7
// 1053.811 us; speedup vs baseline: 2.3974x; 2.3974x over previous
//
#include <hip/hip_runtime.h>

#define NB 64
#define CB 64
#define TB 300
#define VB 25
#define SB 3
#define KB 9
#define LV 28            // padded V stride in LDS (112B rows, 16B aligned)
#define NCNTF 480000.0f  // N*T*V per channel

// ws float offsets
#define WS_SUM1 0
#define WS_SQ1  64
#define WS_SC1  128
#define WS_SH1  192
#define WS_SUM2 256
#define WS_SQ2  320
#define WS_SC2  384
#define WS_SH2  448
#define WS_WTT  512                    // [9][64][64] = 36864 floats
#define WS_AQ   (WS_WTT + 9*64*64)     // [3][25][25]
#define WS_Z_BYTE 262144               // z (bf16): 30.72M * 2B = 61.44MB

__device__ __forceinline__ float bf2f(unsigned short u) {
  unsigned int v = ((unsigned int)u) << 16;
  float f; __builtin_memcpy(&f, &v, 4); return f;
}
__device__ __forceinline__ unsigned short f2bf(float f) {
  unsigned int x; __builtin_memcpy(&x, &f, 4);
  x += 0x7fffu + ((x >> 16) & 1u);
  return (unsigned short)(x >> 16);
}

// ---------------- K0: prep (quantize Aq, WtT transpose, zero stats) ---------
__global__ void k0_prep(const float* __restrict__ A, const float* __restrict__ PA,
                        const float* __restrict__ Wt, float* __restrict__ ws) {
  int tid = threadIdx.x;
  for (int i = tid; i < 512; i += 256) ws[i] = 0.f;
  // WtT[k][i][o] = Wt[o][i][k]
  for (int i = tid; i < KB*CB*CB; i += 256) {
    int o = i & 63, ii = (i >> 6) & 63, k = i >> 12;
    ws[WS_WTT + i] = Wt[(o*64 + ii)*9 + k];
  }
  // Aq = clip(trunc((A+PA)*1024), -32768, 32768) / 1024
  for (int i = tid; i < SB*VB*VB; i += 256) {
    float a = A[i] + PA[i];
    float q = truncf(a * 1024.f);
    q = fminf(fmaxf(q, -32768.f), 32768.f);
    ws[WS_AQ + i] = q * (1.f/1024.f);
  }
}

// ---------------- K1: GCN  z = sum_s Wd[s] @ x @ Aq[s] + bias ---------------
__global__ __launch_bounds__(256) void k1_gcn(
    const float* __restrict__ x, const float* __restrict__ Wd,
    const float* __restrict__ bd, const float* __restrict__ ws,
    float* __restrict__ wstat, unsigned short* __restrict__ zout)
{
  __shared__ __align__(16) float xls[CB][4][LV];   // 28672 B
  __shared__ __align__(16) float aqs[SB*VB*26];    // 7800 B (rows padded to 26)
  __shared__ float s_sum[CB], s_sq[CB];
  int tid = threadIdx.x;
  int t0 = blockIdx.x * 4;                  // 75 * 4 == 300 exact
  int n  = blockIdx.y;

  // stage x tile, flat-index -> coalesced: 64c x 4t x 25v
  // (pad columns v=25..27 are never consumed: u[]/zac[] loops stop at v=24)
  for (int idx = tid; idx < CB*4*VB; idx += 256) {
    int c   = idx / 100;
    int rem = idx - c*100;
    int tl  = rem / 25;
    int v   = rem - tl*25;
    xls[c][tl][v] = x[((size_t)(n*CB + c)*TB + t0 + tl)*VB + v];
  }
  // stage Aq with rows padded to 26
  for (int idx = tid; idx < SB*VB*26; idx += 256) {
    int s = idx / 650, rem = idx - s*650;
    int v = rem / 26, w = rem - v*26;
    aqs[idx] = (w < VB) ? ws[WS_AQ + (s*VB + v)*VB + w] : 0.f;
  }
  if (tid < CB) { s_sum[tid] = 0.f; s_sq[tid] = 0.f; }
  __syncthreads();

  int o  = tid & 63;       // output channel (lane-consecutive)
  int th = tid >> 6;       // timestep within chunk (wave-uniform)
  float zac[VB];
  #pragma unroll
  for (int w = 0; w < VB; ++w) zac[w] = 0.f;

  for (int s = 0; s < SB; ++s) {
    // u[v] = sum_c Wd[s][o][c] * x[c][th][v], c-blocked weights in registers
    float u[VB];
    #pragma unroll
    for (int v = 0; v < VB; ++v) u[v] = 0.f;
    const float* wr = Wd + (size_t)(s*CB + o)*CB;
    for (int cb = 0; cb < CB; cb += 16) {
      float w16[16];
      *(float4*)&w16[0]  = *(const float4*)(wr + cb);
      *(float4*)&w16[4]  = *(const float4*)(wr + cb + 4);
      *(float4*)&w16[8]  = *(const float4*)(wr + cb + 8);
      *(float4*)&w16[12] = *(const float4*)(wr + cb + 12);
      #pragma unroll
      for (int j = 0; j < 16; ++j) {
        float xv[24];
        const float* xr = &xls[cb + j][th][0];
        *(float4*)&xv[0]  = *(const float4*)(xr);
        *(float4*)&xv[4]  = *(const float4*)(xr + 4);
        *(float4*)&xv[8]  = *(const float4*)(xr + 8);
        *(float4*)&xv[12] = *(const float4*)(xr + 12);
        *(float4*)&xv[16] = *(const float4*)(xr + 16);
        *(float4*)&xv[20] = *(const float4*)(xr + 20);
        float x24 = xr[24];
        float wj = w16[j];
        #pragma unroll
        for (int v = 0; v < 24; ++v)
          u[v] = fmaf(wj, xv[v], u[v]);
        u[24] = fmaf(wj, x24, u[24]);
      }
    }
    // zac[w] += sum_v u[v] * Aq[s][v][w]  (rows padded to 26 -> float2 reads)
    #pragma unroll
    for (int v = 0; v < VB; ++v) {
      float ar[26];
      const float* arow = &aqs[(s*VB + v)*26];
      #pragma unroll
      for (int j = 0; j < 13; ++j)
        *(float2*)&ar[j*2] = *(const float2*)(arow + j*2);
      float uv = u[v];
      #pragma unroll
      for (int w = 0; w < VB; ++w)
        zac[w] = fmaf(uv, ar[w], zac[w]);
    }
  }

  int t = t0 + th;   // always < 300
  {
    float bsum = bd[o] + bd[CB + o] + bd[2*CB + o];
    unsigned short* zr = zout + (((size_t)n*CB + o)*TB + t)*VB;
    float sm = 0.f, sq = 0.f;
    #pragma unroll
    for (int w = 0; w < VB; ++w) {
      float zv = zac[w] + bsum;
      zr[w] = f2bf(zv);
      sm += zv; sq += zv*zv;
    }
    atomicAdd(&s_sum[o], sm);
    atomicAdd(&s_sq[o], sq);
  }
  __syncthreads();
  if (tid < CB) {
    atomicAdd(&wstat[WS_SUM1 + tid], s_sum[tid]);
    atomicAdd(&wstat[WS_SQ1  + tid], s_sq[tid]);
  }
}

// ---------------- K2/K4: fold BN stats into scale/shift ---------------------
__global__ void k_fin(const float* __restrict__ g, const float* __restrict__ b,
                      float* __restrict__ ws, int soff) {
  int c = threadIdx.x;
  float m   = ws[soff + c] * (1.f/NCNTF);
  float var = ws[soff + 64 + c] * (1.f/NCNTF) - m*m;
  float rstd = rsqrtf(var + 1e-5f);
  float sc = rstd * g[c];
  ws[soff + 128 + c] = sc;
  ws[soff + 192 + c] = b[c] - m * sc;
}

// ---------------- K3: y = relu(bn1(z)+x) on the fly; 9-tap temporal conv ----
__global__ __launch_bounds__(256) void k3_tconv(
    const float* __restrict__ x, const unsigned short* __restrict__ z,
    const float* __restrict__ bt, const float* __restrict__ ws,
    float* __restrict__ wstat, float* __restrict__ tcout)
{
  __shared__ __align__(16) float yls[16][16][LV];  // 28672 B
  __shared__ float s_sum[CB], s_sq[CB];
  int tid = threadIdx.x;
  int t0 = blockIdx.x * 8;
  int n  = blockIdx.y;
  int o4 = tid & 15;          // o = o4*4 + a
  int th = (tid >> 4) & 7;    // output timestep within chunk
  int vh = tid >> 7;          // v half
  int v0 = vh * 12;           // overlap col 12, masked at emit (48B: 16B-aligned)

  float acc0[13], acc1[13], acc2[13], acc3[13];
  #pragma unroll
  for (int b = 0; b < 13; ++b) { acc0[b]=0.f; acc1[b]=0.f; acc2[b]=0.f; acc3[b]=0.f; }
  if (tid < CB) { s_sum[tid] = 0.f; s_sq[tid] = 0.f; }

  const float* wtt = ws + WS_WTT;
  for (int ih = 0; ih < 4; ++ih) {
    __syncthreads();
    // stage y quarter-tile, flat-index -> coalesced: 16i x 16t x 25v
    // (pad columns v=25..27 never consumed: reads cover v0..v0+12 <= 24)
    for (int idx = tid; idx < 16*16*VB; idx += 256) {
      int il  = idx / 400;
      int rem = idx - il*400;
      int tl  = rem / 25;
      int v   = rem - tl*25;
      int i   = ih*16 + il;
      int gt  = t0 + tl - 4;
      float y = 0.f;
      if (gt >= 0 && gt < TB) {
        size_t base = ((size_t)(n*CB + i)*TB + gt)*VB + v;
        float zv = bf2f(z[base]);
        y = fmaxf(fmaf(zv, ws[WS_SC1 + i], ws[WS_SH1 + i]) + x[base], 0.f);
      }
      yls[il][tl][v] = y;
    }
    __syncthreads();
    for (int i = 0; i < 16; ++i) {
      // all 9 taps' weights for this (i, o-quad): 9 independent float4 loads
      float w[36];
      #pragma unroll
      for (int k = 0; k < KB; ++k)
        *(float4*)&w[k*4] = *(const float4*)(wtt + ((size_t)(k*CB + ih*16 + i))*CB + o4*4);
      #pragma unroll
      for (int k = 0; k < KB; ++k) {
        float yv[13];
        const float* yr = &yls[i][th + k][v0];
        *(float4*)&yv[0] = *(const float4*)(yr);
        *(float4*)&yv[4] = *(const float4*)(yr + 4);
        *(float4*)&yv[8] = *(const float4*)(yr + 8);
        yv[12] = yr[12];
        #pragma unroll
        for (int b = 0; b < 13; ++b) {
          float yy = yv[b];
          acc0[b] = fmaf(w[k*4+0], yy, acc0[b]);
          acc1[b] = fmaf(w[k*4+1], yy, acc1[b]);
          acc2[b] = fmaf(w[k*4+2], yy, acc2[b]);
          acc3[b] = fmaf(w[k*4+3], yy, acc3[b]);
        }
      }
    }
  }

  int t = t0 + th;
  if (t < TB) {
#define EMITC(A_, ACC_) { \
    int o = o4*4 + (A_); \
    float bta = bt[o]; \
    float* tr = tcout + (((size_t)n*CB + o)*TB + t)*VB; \
    float sm = 0.f, sq = 0.f; \
    _Pragma("unroll") \
    for (int b = 0; b < 13; ++b) { \
      if (vh == 0 || b > 0) { \
        int v = v0 + b; \
        float val = ACC_[b] + bta; \
        tr[v] = val; sm += val; sq += val*val; } } \
    atomicAdd(&s_sum[o], sm); atomicAdd(&s_sq[o], sq); }
    EMITC(0, acc0) EMITC(1, acc1) EMITC(2, acc2) EMITC(3, acc3)
#undef EMITC
  }
  __syncthreads();
  if (tid < CB) {
    atomicAdd(&wstat[WS_SUM2 + tid], s_sum[tid]);
    atomicAdd(&wstat[WS_SQ2  + tid], s_sq[tid]);
  }
}

// ---------------- K5: out = relu(bn2(tc) + x), in-place on d_out (f32) ------
__global__ void k5_final(const float* __restrict__ x, const float* __restrict__ ws,
                         float* __restrict__ out) {
  int idx = blockIdx.x * blockDim.x + threadIdx.x;
  int stride = gridDim.x * blockDim.x;
  const int total4 = NB*CB*TB*VB/4;   // 7500 per (n,c) plane, /4 = 1875 exact
  for (int i = idx; i < total4; i += stride) {
    int c = (i / 1875) & 63;
    float sc = ws[WS_SC2 + c], sh = ws[WS_SH2 + c];
    float4 t4 = ((const float4*)out)[i];
    float4 x4 = ((const float4*)x)[i];
    float4 r;
    r.x = fmaxf(fmaf(t4.x, sc, sh) + x4.x, 0.f);
    r.y = fmaxf(fmaf(t4.y, sc, sh) + x4.y, 0.f);
    r.z = fmaxf(fmaf(t4.z, sc, sh) + x4.z, 0.f);
    r.w = fmaxf(fmaf(t4.w, sc, sh) + x4.w, 0.f);
    ((float4*)out)[i] = r;
  }
}

extern "C" void kernel_launch(void* const* d_in, const int* in_sizes, int n_in,
                              void* d_out, int out_size, void* d_ws, size_t ws_size,
                              hipStream_t stream) {
  const float* x  = (const float*)d_in[0];
  const float* A  = (const float*)d_in[1];
  const float* PA = (const float*)d_in[2];
  const float* Wd = (const float*)d_in[3];
  const float* bd = (const float*)d_in[4];
  const float* g1 = (const float*)d_in[5];
  const float* b1 = (const float*)d_in[6];
  const float* Wt = (const float*)d_in[7];
  const float* bt = (const float*)d_in[8];
  const float* g2 = (const float*)d_in[9];
  const float* b2 = (const float*)d_in[10];

  float* ws = (float*)d_ws;
  unsigned short* zbuf = (unsigned short*)((char*)d_ws + WS_Z_BYTE);
  float* out = (float*)d_out;

  k0_prep<<<dim3(1), dim3(256), 0, stream>>>(A, PA, Wt, ws);
  k1_gcn<<<dim3(75, 64), dim3(256), 0, stream>>>(x, Wd, bd, ws, ws, zbuf);
  k_fin<<<dim3(1), dim3(64), 0, stream>>>(g1, b1, ws, 0);
  k3_tconv<<<dim3(38, 64), dim3(256), 0, stream>>>(x, zbuf, bt, ws, ws, out);
  k_fin<<<dim3(1), dim3(64), 0, stream>>>(g2, b2, ws, 256);
  k5_final<<<dim3(2048), dim3(256), 0, stream>>>(x, ws, out);
}

// Round 8
// 855.400 us; speedup vs baseline: 2.9535x; 1.2320x over previous
//
#include <hip/hip_runtime.h>

#define NB 64
#define CB 64
#define TB 300
#define VB 25
#define SB 3
#define KB 9
#define NCNTF 480000.0f  // N*T*V per channel

// ws float offsets (stats block)
#define WS_SUM1 0
#define WS_SQ1  64
#define WS_SC1  128
#define WS_SH1  192
#define WS_SUM2 256
#define WS_SQ2  320
#define WS_SC2  384
#define WS_SH2  448
// ws byte offsets
#define WS_WTP_BYTE 2048              // packed A-frags: 18*4*64*8 bf16 = 73728 B
#define WS_AQ_F     18944             // float offset: Aq [3][25][25]
#define WS_TC_BYTE  262144            // tc bf16 [n][t][v][o]: 61.44 MB
// d_out scratch layout (ushort elements)
#define ZP_ELEMS    30720000          // z' bf16 [n][t][v][c] at d_out[0]
                                      // xT bf16 [n][t][v][c] at d_out[ZP_ELEMS]

typedef __attribute__((ext_vector_type(8))) short short8v;
typedef __attribute__((ext_vector_type(4))) float f32x4;

__device__ __forceinline__ float bf2f(unsigned short u) {
  unsigned int v = ((unsigned int)u) << 16;
  float f; __builtin_memcpy(&f, &v, 4); return f;
}
__device__ __forceinline__ unsigned short f2bf(float f) {
  unsigned int x; __builtin_memcpy(&x, &f, 4);
  x += 0x7fffu + ((x >> 16) & 1u);
  return (unsigned short)(x >> 16);
}

// ---------------- K0: prep (quantize Aq, pack Wt A-frags, zero stats) -------
__global__ void k0_prep(const float* __restrict__ A, const float* __restrict__ PA,
                        const float* __restrict__ Wt, float* __restrict__ ws) {
  int tid = threadIdx.x;
  for (int i = tid; i < 512; i += 256) ws[i] = 0.f;
  // WtP[kt=tap*2+ih][g][oc][j] = bf16(Wt[oc][ih*32+g*8+j][tap]), 18*4*64*8
  unsigned short* wtp = (unsigned short*)((char*)ws + WS_WTP_BYTE);
  for (int idx = tid; idx < 18*4*64*8; idx += 256) {
    int j  = idx & 7;
    int oc = (idx >> 3) & 63;
    int g  = (idx >> 9) & 3;
    int kt = idx >> 11;
    int tap = kt >> 1, ih = kt & 1;
    wtp[idx] = f2bf(Wt[(oc*64 + ih*32 + g*8 + j)*9 + tap]);
  }
  // Aq = clip(trunc((A+PA)*1024), -32768, 32768) / 1024
  for (int i = tid; i < SB*VB*VB; i += 256) {
    float a = A[i] + PA[i];
    float q = truncf(a * 1024.f);
    q = fminf(fmaxf(q, -32768.f), 32768.f);
    ws[WS_AQ_F + i] = q * (1.f/1024.f);
  }
}

// ---------------- K_XT: xT[n][t][v][c] = bf16(x[n][c][t][v]) ----------------
__global__ __launch_bounds__(256) void k_xt(const float* __restrict__ x,
                                            unsigned short* __restrict__ xt) {
  __shared__ float xl[64*201];
  int tid = threadIdx.x;
  int t0 = blockIdx.x * 8;
  int n  = blockIdx.y;
  int lim = 7500 - t0*25; if (lim > 200) lim = 200;   // valid tv count
  for (int idx = tid; idx < 64*200; idx += 256) {
    int c = idx / 200, tv = idx - c*200;
    if (tv < lim)
      xl[c*201 + tv] = x[(size_t)(n*64 + c)*7500 + t0*25 + tv];
  }
  __syncthreads();
  int base = n*480000 + t0*1600;
  for (int idx = tid; idx < 200*64; idx += 256) {
    int tv = idx >> 6, c = idx & 63;
    if (tv < lim)
      xt[base + idx] = f2bf(xl[c*201 + tv]);
  }
}

// ---------------- K1: GCN  z' = sum_s Wd[s] @ x @ Aq[s] + bias --------------
// writes z' bf16 in [n][t][v][c] layout
__global__ __launch_bounds__(256) void k1_gcn(
    const float* __restrict__ x, const float* __restrict__ Wd,
    const float* __restrict__ bd, const float* __restrict__ ws,
    float* __restrict__ wstat, unsigned short* __restrict__ zout)
{
  __shared__ __align__(16) float xls[CB][4][28];   // 28672 B
  __shared__ __align__(16) float aqs[SB*VB*26];    // 7800 B
  __shared__ float s_sum[CB], s_sq[CB];
  int tid = threadIdx.x;
  int t0 = blockIdx.x * 4;                  // 75*4 == 300 exact
  int n  = blockIdx.y;

  for (int idx = tid; idx < CB*4*VB; idx += 256) {
    int c   = idx / 100;
    int rem = idx - c*100;
    int tl  = rem / 25;
    int v   = rem - tl*25;
    xls[c][tl][v] = x[((size_t)(n*CB + c)*TB + t0 + tl)*VB + v];
  }
  for (int idx = tid; idx < SB*VB*26; idx += 256) {
    int s = idx / 650, rem = idx - s*650;
    int v = rem / 26, w = rem - v*26;
    aqs[idx] = (w < VB) ? ws[WS_AQ_F + (s*VB + v)*VB + w] : 0.f;
  }
  if (tid < CB) { s_sum[tid] = 0.f; s_sq[tid] = 0.f; }
  __syncthreads();

  int o  = tid & 63;
  int th = tid >> 6;
  float zac[VB];
  #pragma unroll
  for (int w = 0; w < VB; ++w) zac[w] = 0.f;

  for (int s = 0; s < SB; ++s) {
    float u[VB];
    #pragma unroll
    for (int v = 0; v < VB; ++v) u[v] = 0.f;
    const float* wr = Wd + (size_t)(s*CB + o)*CB;
    for (int cb = 0; cb < CB; cb += 16) {
      float w16[16];
      *(float4*)&w16[0]  = *(const float4*)(wr + cb);
      *(float4*)&w16[4]  = *(const float4*)(wr + cb + 4);
      *(float4*)&w16[8]  = *(const float4*)(wr + cb + 8);
      *(float4*)&w16[12] = *(const float4*)(wr + cb + 12);
      #pragma unroll
      for (int j = 0; j < 16; ++j) {
        float xv[24];
        const float* xr = &xls[cb + j][th][0];
        *(float4*)&xv[0]  = *(const float4*)(xr);
        *(float4*)&xv[4]  = *(const float4*)(xr + 4);
        *(float4*)&xv[8]  = *(const float4*)(xr + 8);
        *(float4*)&xv[12] = *(const float4*)(xr + 12);
        *(float4*)&xv[16] = *(const float4*)(xr + 16);
        *(float4*)&xv[20] = *(const float4*)(xr + 20);
        float x24 = xr[24];
        float wj = w16[j];
        #pragma unroll
        for (int v = 0; v < 24; ++v)
          u[v] = fmaf(wj, xv[v], u[v]);
        u[24] = fmaf(wj, x24, u[24]);
      }
    }
    #pragma unroll
    for (int v = 0; v < VB; ++v) {
      float ar[26];
      const float* arow = &aqs[(s*VB + v)*26];
      #pragma unroll
      for (int j = 0; j < 13; ++j)
        *(float2*)&ar[j*2] = *(const float2*)(arow + j*2);
      float uv = u[v];
      #pragma unroll
      for (int w = 0; w < VB; ++w)
        zac[w] = fmaf(uv, ar[w], zac[w]);
    }
  }

  int t = t0 + th;
  {
    float bsum = bd[o] + bd[CB + o] + bd[2*CB + o];
    unsigned short* zr = zout + n*480000 + t*1600 + o;
    float sm = 0.f, sq = 0.f;
    #pragma unroll
    for (int w = 0; w < VB; ++w) {
      float zv = zac[w] + bsum;
      zr[w*64] = f2bf(zv);
      sm += zv; sq += zv*zv;
    }
    atomicAdd(&s_sum[o], sm);
    atomicAdd(&s_sq[o], sq);
  }
  __syncthreads();
  if (tid < CB) {
    atomicAdd(&wstat[WS_SUM1 + tid], s_sum[tid]);
    atomicAdd(&wstat[WS_SQ1  + tid], s_sq[tid]);
  }
}

// ---------------- K2/K4: fold BN stats into scale/shift ---------------------
__global__ void k_fin(const float* __restrict__ g, const float* __restrict__ b,
                      float* __restrict__ ws, int soff) {
  int c = threadIdx.x;
  float m   = ws[soff + c] * (1.f/NCNTF);
  float var = ws[soff + 64 + c] * (1.f/NCNTF) - m*m;
  float rstd = rsqrtf(var + 1e-5f);
  float sc = rstd * g[c];
  ws[soff + 128 + c] = sc;
  ws[soff + 192 + c] = b[c] - m * sc;
}

// ---------------- K3: MFMA temporal conv ------------------------------------
// y = relu(sc1*z' + sh1 + xT) built in LDS (bf16, XOR-swizzled, [tv][i]);
// tc[o][tv] = sum_{i,k} Wt[o][i][k] * y[i][tv + 25k]; bias+stats; bf16 store.
__global__ __launch_bounds__(256) void k3_mfma(
    const unsigned short* __restrict__ zb, const unsigned short* __restrict__ xtb,
    const float* __restrict__ bt, const float* __restrict__ ws,
    float* __restrict__ wstat, unsigned short* __restrict__ tco)
{
  __shared__ __align__(16) char ubuf[51456];      // yT (51200) / tc_lds (51456)
  __shared__ float s_sum[CB], s_sq[CB];
  int tid = threadIdx.x;
  int t0 = blockIdx.x * 8;                        // 38 blocks, t0 up to 296
  int n  = blockIdx.y;
  int l  = tid & 63;
  int mt = tid >> 6;
  int r  = l & 15;
  int g  = l >> 4;

  if (tid < CB) { s_sum[tid] = 0.f; s_sq[tid] = 0.f; }

  // --- A-fragments: 18 K-tiles, preloaded (independent 16B loads) ---
  const unsigned short* wtp = (const unsigned short*)((const char*)ws + WS_WTP_BYTE);
  short8v afr[18];
  #pragma unroll
  for (int kt = 0; kt < 18; ++kt)
    afr[kt] = *(const short8v*)(wtp + ((size_t)((kt*4 + g)*64 + mt*16 + r)) * 8);

  // --- stage yT: 400 tv-rows x 64 i (bf16), swizzled ---
  {
    float sc1 = ws[WS_SC1 + l], sh1 = ws[WS_SH1 + l];
    int addr = n*480000 + (t0 - 4)*1600 + tid;    // linear: base + tv*64 + i
    int tv = tid >> 6;
    int vv = tv;                                   // v within row (trow=0)
    int gt = t0 - 4;
    for (int it = 0; it < 100; ++it) {
      float y = 0.f;
      if (gt >= 0 && gt < TB) {
        float zv = bf2f(zb[addr]);
        float xv = bf2f(xtb[addr]);
        y = fmaxf(fmaf(zv, sc1, sh1) + xv, 0.f);
      }
      int wb = (tv << 7) + (((l << 1)) ^ ((tv & 7) << 4));
      *(unsigned short*)(ubuf + wb) = f2bf(y);
      addr += 256; tv += 4;
      vv += 4; if (vv >= 25) { vv -= 25; ++gt; }
    }
  }
  __syncthreads();

  // --- MFMA main loop: 18 K-tiles x 13 col-tiles ---
  f32x4 acc[13];
  #pragma unroll
  for (int ct = 0; ct < 13; ++ct) acc[ct] = (f32x4){0.f, 0.f, 0.f, 0.f};
  int delta12 = (r < 8) ? 12*2048 : -1024;        // col-tile 12 wrap (j_eff)
  #pragma unroll
  for (int kt = 0; kt < 18; ++kt) {
    int tap = kt >> 1, ih = kt & 1;
    int tv0 = r + 25*tap;
    int ab = (tv0 << 7) + (((ih << 6) + (g << 4)) ^ ((tv0 & 7) << 4));
    const char* pb = ubuf + ab;
    #pragma unroll
    for (int ct = 0; ct < 12; ++ct) {
      short8v b = *(const short8v*)(pb + ct*2048);
      acc[ct] = __builtin_amdgcn_mfma_f32_16x16x32_bf16(afr[kt], b, acc[ct], 0, 0, 0);
    }
    short8v b12 = *(const short8v*)(pb + delta12);
    acc[12] = __builtin_amdgcn_mfma_f32_16x16x32_bf16(afr[kt], b12, acc[12], 0, 0, 0);
  }
  __syncthreads();

  // --- C-frags -> LDS [o][201] f32 ---
  float* tcl = (float*)ubuf;
  #pragma unroll
  for (int ct = 0; ct < 13; ++ct) {
    int j = ct*16 + r;
    if (ct < 12 || r < 8) {
      int row0 = mt*16 + g*4;
      #pragma unroll
      for (int reg = 0; reg < 4; ++reg)
        tcl[(row0 + reg)*201 + j] = acc[ct][reg];
    }
  }
  __syncthreads();

  // --- bias + BN2 stats + bf16 store ([n][t][v][o]) ---
  {
    int o = tid & 63, ch = tid >> 6;
    float bto = bt[o];
    int lim = 7500 - t0*25; if (lim > 200) lim = 200;
    int wsbase = n*480000 + t0*1600 + o;
    float sm = 0.f, sq = 0.f;
    for (int q = 0; q < 50; ++q) {
      int tv = ch*50 + q;
      if (tv < lim) {
        float val = tcl[o*201 + tv] + bto;
        tco[wsbase + tv*64] = f2bf(val);
        sm += val; sq += val*val;
      }
    }
    atomicAdd(&s_sum[o], sm);
    atomicAdd(&s_sq[o], sq);
  }
  __syncthreads();
  if (tid < CB) {
    atomicAdd(&wstat[WS_SUM2 + tid], s_sum[tid]);
    atomicAdd(&wstat[WS_SQ2  + tid], s_sq[tid]);
  }
}

// ---------------- K5: out = relu(bn2(tc) + x), full f32 d_out ---------------
__global__ __launch_bounds__(256) void k5_final(
    const float* __restrict__ x, const float* __restrict__ ws,
    const unsigned short* __restrict__ tc, float* __restrict__ out)
{
  __shared__ float tl5[200*65];
  int tid = threadIdx.x;
  int t0 = blockIdx.x * 8;
  int n  = blockIdx.y;
  int lim = 7500 - t0*25; if (lim > 200) lim = 200;
  int base = n*480000 + t0*1600;
  for (int idx = tid; idx < 200*64; idx += 256) {
    int tv = idx >> 6, o = idx & 63;
    if (tv < lim)
      tl5[tv*65 + o] = bf2f(tc[base + idx]);
  }
  __syncthreads();
  int w = tid >> 6, lane = tid & 63;
  for (int ol = 0; ol < 16; ++ol) {
    int o = w*16 + ol;
    float sc = ws[WS_SC2 + o], sh = ws[WS_SH2 + o];
    size_t gb = (size_t)(n*64 + o)*7500 + t0*25;
    #pragma unroll
    for (int c2 = 0; c2 < 4; ++c2) {
      int tv = c2*64 + lane;
      if (tv < lim) {
        float val = fmaf(tl5[tv*65 + o], sc, sh) + x[gb + tv];
        out[gb + tv] = fmaxf(val, 0.f);
      }
    }
  }
}

extern "C" void kernel_launch(void* const* d_in, const int* in_sizes, int n_in,
                              void* d_out, int out_size, void* d_ws, size_t ws_size,
                              hipStream_t stream) {
  const float* x  = (const float*)d_in[0];
  const float* A  = (const float*)d_in[1];
  const float* PA = (const float*)d_in[2];
  const float* Wd = (const float*)d_in[3];
  const float* bd = (const float*)d_in[4];
  const float* g1 = (const float*)d_in[5];
  const float* b1 = (const float*)d_in[6];
  const float* Wt = (const float*)d_in[7];
  const float* bt = (const float*)d_in[8];
  const float* g2 = (const float*)d_in[9];
  const float* b2 = (const float*)d_in[10];

  float* ws = (float*)d_ws;
  unsigned short* zbuf = (unsigned short*)d_out;            // z' scratch
  unsigned short* xtb  = (unsigned short*)d_out + ZP_ELEMS; // xT scratch
  unsigned short* tc   = (unsigned short*)((char*)d_ws + WS_TC_BYTE);
  float* out = (float*)d_out;

  k0_prep<<<dim3(1), dim3(256), 0, stream>>>(A, PA, Wt, ws);
  k_xt<<<dim3(38, 64), dim3(256), 0, stream>>>(x, xtb);
  k1_gcn<<<dim3(75, 64), dim3(256), 0, stream>>>(x, Wd, bd, ws, ws, zbuf);
  k_fin<<<dim3(1), dim3(64), 0, stream>>>(g1, b1, ws, 0);
  k3_mfma<<<dim3(38, 64), dim3(256), 0, stream>>>(zbuf, xtb, bt, ws, ws, tc);
  k_fin<<<dim3(1), dim3(64), 0, stream>>>(g2, b2, ws, 256);
  k5_final<<<dim3(38, 64), dim3(256), 0, stream>>>(x, ws, tc, out);
}

// Round 9
// 650.958 us; speedup vs baseline: 3.8811x; 1.3141x over previous
//
#include <hip/hip_runtime.h>

#define NB 64
#define CB 64
#define TB 300
#define VB 25
#define SB 3
#define KB 9
#define NCNTF 480000.0f  // N*T*V per channel

// ws float offsets (stats block)
#define WS_SUM1 0
#define WS_SQ1  64
#define WS_SC1  128
#define WS_SH1  192
#define WS_SUM2 256
#define WS_SQ2  320
#define WS_SC2  384
#define WS_SH2  448
// ws byte offsets
#define WS_WTP_BYTE 2048              // k3 A-frags: 18*4*64*8 bf16 = 73728 B
#define WS_AQP_BYTE 75776             // k1 stage1 A-frags (Aq hi/lo): 12*64*8 bf16
#define WS_WDP_BYTE 88064             // k1 stage2 A-frags (Wd hi/lo): 48*64*8 bf16
#define WS_TC_BYTE  262144            // tc bf16 [n][t][v][o]: 61.44 MB
// d_out scratch layout (ushort elements)
#define ZP_ELEMS    30720000          // z' bf16 [n][t][v][c] at d_out[0]
                                      // xT bf16 [n][t][v][c] at d_out[ZP_ELEMS]

typedef __attribute__((ext_vector_type(8))) short short8v;
typedef __attribute__((ext_vector_type(4))) float f32x4;

__device__ __forceinline__ float bf2f(unsigned short u) {
  unsigned int v = ((unsigned int)u) << 16;
  float f; __builtin_memcpy(&f, &v, 4); return f;
}
__device__ __forceinline__ unsigned short f2bf(float f) {
  unsigned int x; __builtin_memcpy(&x, &f, 4);
  x += 0x7fffu + ((x >> 16) & 1u);
  return (unsigned short)(x >> 16);
}

// ---------------- K0: prep (pack Wt, Aq hi/lo, Wd hi/lo; zero stats) --------
__global__ void k0_prep(const float* __restrict__ A, const float* __restrict__ PA,
                        const float* __restrict__ Wd, const float* __restrict__ Wt,
                        float* __restrict__ ws) {
  int gid = blockIdx.x * 256 + threadIdx.x;
  int gs  = gridDim.x * 256;
  for (int i = gid; i < 512; i += gs) ws[i] = 0.f;
  // WtP[kt=tap*2+ih][g][oc][j] = bf16(Wt[oc][ih*32+g*8+j][tap])
  unsigned short* wtp = (unsigned short*)((char*)ws + WS_WTP_BYTE);
  for (int idx = gid; idx < 18*4*64*8; idx += gs) {
    int j  = idx & 7;
    int oc = (idx >> 3) & 63;
    int g  = (idx >> 9) & 3;
    int kt = idx >> 11;
    int tap = kt >> 1, ih = kt & 1;
    wtp[idx] = f2bf(Wt[(oc*64 + ih*32 + g*8 + j)*9 + tap]);
  }
  // AqP: frag f = s*4 + wt*2 + h; lane l; elem j: A[row=w][k=v] hi/lo split
  unsigned short* aqp = (unsigned short*)((char*)ws + WS_AQP_BYTE);
  for (int idx = gid; idx < 12*64*8; idx += gs) {
    int j = idx & 7, l = (idx >> 3) & 63, fi = idx >> 9;
    int h = fi & 1, wt = (fi >> 1) & 1, s = fi >> 2;
    int v = (l >> 4)*8 + j, w = wt*16 + (l & 15);
    unsigned short out = 0;
    if (v < VB && w < VB) {
      int ai = (s*VB + v)*VB + w;
      float a = A[ai] + PA[ai];
      float q = truncf(a * 1024.f);
      q = fminf(fmaxf(q, -32768.f), 32768.f);
      float aq = q * (1.f/1024.f);
      unsigned short hi = f2bf(aq);
      out = h ? f2bf(aq - bf2f(hi)) : hi;
    }
    aqp[idx] = out;
  }
  // WdP: frag fi = (h*6+kt)*4 + mt; A[row=o][k=s*64+c] hi/lo split
  unsigned short* wdp = (unsigned short*)((char*)ws + WS_WDP_BYTE);
  for (int idx = gid; idx < 48*64*8; idx += gs) {
    int j = idx & 7, l = (idx >> 3) & 63, fi = idx >> 9;
    int mt = fi & 3, q2 = fi >> 2;
    int kt = q2 % 6, h = q2 / 6;
    int k = kt*32 + (l >> 4)*8 + j;
    int s = k >> 6, c = k & 63, o = mt*16 + (l & 15);
    float wv = Wd[(s*64 + o)*64 + c];
    unsigned short hi = f2bf(wv);
    wdp[idx] = h ? f2bf(wv - bf2f(hi)) : hi;
  }
}

// ---------------- K_XT: xT[n][t][v][c] = bf16(x[n][c][t][v]) ----------------
__global__ __launch_bounds__(256) void k_xt(const float* __restrict__ x,
                                            unsigned short* __restrict__ xt) {
  __shared__ float xl[64*201];
  int tid = threadIdx.x;
  int t0 = blockIdx.x * 8;
  int n  = blockIdx.y;
  int lim = 7500 - t0*25; if (lim > 200) lim = 200;   // valid tv count
  for (int idx = tid; idx < 64*200; idx += 256) {
    int c = idx / 200, tv = idx - c*200;
    if (tv < lim)
      xl[c*201 + tv] = x[(size_t)(n*64 + c)*7500 + t0*25 + tv];
  }
  __syncthreads();
  int base = n*480000 + t0*1600;
  for (int idx = tid; idx < 200*64; idx += 256) {
    int tv = idx >> 6, c = idx & 63;
    if (tv < lim)
      xt[base + idx] = f2bf(xl[c*201 + tv]);
  }
}

// ---------------- K1: MFMA GCN  z' = sum_s Wd[s] @ x @ Aq[s] + bias ---------
// stage1: xa[tw][s,c] = Aq^T X^T (MFMA, Aq exact hi/lo); stage2: K=192 GEMM.
__global__ __launch_bounds__(256) void k1_gcn(
    const float* __restrict__ x, const float* __restrict__ bd,
    const float* __restrict__ ws, float* __restrict__ wstat,
    unsigned short* __restrict__ zout)
{
  __shared__ __align__(16) char k1lds[33792 + 43008];
  __shared__ float s_sum[CB], s_sq[CB];
  float* xls = (float*)k1lds;            // [4t][64c][33v] f32
  char*  xab = k1lds + 33792;            // xa bf16 [112 rows][384 B] swizzled
  float* zg  = (float*)k1lds;            // reuse: [100 tw][65 o] f32
  int tid = threadIdx.x;
  int t0 = blockIdx.x * 4;               // 75*4 == 300 exact
  int n  = blockIdx.y;
  int wv = tid >> 6, l = tid & 63, r = l & 15, g = l >> 4;

  if (tid < CB) { s_sum[tid] = 0.f; s_sq[tid] = 0.f; }
  // stage x tile f32: [tl][c][33] (stride 33 -> conflict-free)
  for (int idx = tid; idx < 6400; idx += 256) {
    int c = idx / 100, rem = idx - c*100, tl = rem / 25, v = rem - tl*25;
    xls[(tl*64 + c)*33 + v] = x[((size_t)(n*64 + c)*300 + t0 + tl)*25 + v];
  }
  for (int idx = tid; idx < 1792; idx += 256) {   // zero pad v=25..31
    int tl = idx / 448, rem = idx - tl*448, c = rem / 7, v = 25 + rem - c*7;
    xls[(tl*64 + c)*33 + v] = 0.f;
  }
  __syncthreads();

  const unsigned short* aqp = (const unsigned short*)((const char*)ws + WS_AQP_BYTE);
  const unsigned short* wdp = (const unsigned short*)((const char*)ws + WS_WDP_BYTE);

  // B1 fragments: B[k=v][col=c] from xls (wave wv owns t=wv)
  short8v b1[4];
  #pragma unroll
  for (int ct = 0; ct < 4; ++ct) {
    int c = ct*16 + r;
    #pragma unroll
    for (int j = 0; j < 8; ++j)
      b1[ct][j] = (short)f2bf(xls[(wv*64 + c)*33 + g*8 + j]);
  }

  // ---- stage1: per s, xa[w][c] = sum_v Aq[s][v][w] * x[c][v] ----
  for (int s = 0; s < SB; ++s) {
    short8v a1[4];
    #pragma unroll
    for (int q = 0; q < 4; ++q)
      a1[q] = *(const short8v*)(aqp + ((s*4 + q)*64 + l)*8);
    f32x4 acc1[8];
    #pragma unroll
    for (int i = 0; i < 8; ++i) acc1[i] = (f32x4){0.f,0.f,0.f,0.f};
    #pragma unroll
    for (int wt = 0; wt < 2; ++wt)
      #pragma unroll
      for (int ct = 0; ct < 4; ++ct) {
        acc1[wt*4+ct] = __builtin_amdgcn_mfma_f32_16x16x32_bf16(a1[wt*2+0], b1[ct], acc1[wt*4+ct], 0,0,0);
        acc1[wt*4+ct] = __builtin_amdgcn_mfma_f32_16x16x32_bf16(a1[wt*2+1], b1[ct], acc1[wt*4+ct], 0,0,0);
      }
    // C -> xa LDS (bf16, XOR-swizzled 16B granules)
    #pragma unroll
    for (int wt = 0; wt < 2; ++wt)
      #pragma unroll
      for (int ct = 0; ct < 4; ++ct)
        #pragma unroll
        for (int reg = 0; reg < 4; ++reg) {
          int w = wt*16 + g*4 + reg;
          if (w < VB) {
            int row = wv*25 + w, c = ct*16 + r;
            int bir = (s*128 + c*2) ^ ((row & 7) << 4);
            *(unsigned short*)(xab + row*384 + bir) = f2bf(acc1[wt*4+ct][reg]);
          }
        }
  }
  __syncthreads();

  // ---- stage2: z[o][tw] = sum_{s,c} Wd * xa, K=192 ----
  short8v a2[12];
  #pragma unroll
  for (int h = 0; h < 2; ++h)
    #pragma unroll
    for (int kt = 0; kt < 6; ++kt)
      a2[h*6+kt] = *(const short8v*)(wdp + (((h*6 + kt)*4 + wv)*64 + l)*8);
  f32x4 acc2[7];
  #pragma unroll
  for (int i = 0; i < 7; ++i) acc2[i] = (f32x4){0.f,0.f,0.f,0.f};
  for (int kt = 0; kt < 6; ++kt) {
    #pragma unroll
    for (int ct = 0; ct < 7; ++ct) {
      int row = ct*16 + r;
      int bir = (kt*64 + g*16) ^ ((r & 7) << 4);
      short8v b = *(const short8v*)(xab + row*384 + bir);
      acc2[ct] = __builtin_amdgcn_mfma_f32_16x16x32_bf16(a2[kt],   b, acc2[ct], 0,0,0);
      acc2[ct] = __builtin_amdgcn_mfma_f32_16x16x32_bf16(a2[6+kt], b, acc2[ct], 0,0,0);
    }
  }
  // C -> zg (reuses xls region; all xls reads finished pre-barrier)
  #pragma unroll
  for (int ct = 0; ct < 7; ++ct) {
    int tw = ct*16 + r;
    if (tw < 100) {
      #pragma unroll
      for (int reg = 0; reg < 4; ++reg)
        zg[tw*65 + wv*16 + g*4 + reg] = acc2[ct][reg];
    }
  }
  __syncthreads();

  // epilogue: bias + BN1 stats + coalesced bf16 z' store ([n][t][v][c])
  {
    int o = tid & 63, chunk = tid >> 6;
    float bsum = bd[o] + bd[CB + o] + bd[2*CB + o];
    unsigned short* zr = zout + n*480000 + t0*25*64 + o;
    float sm = 0.f, sq = 0.f;
    for (int q = 0; q < 25; ++q) {
      int tw = chunk*25 + q;
      float val = zg[tw*65 + o] + bsum;
      zr[tw*64] = f2bf(val);
      sm += val; sq += val*val;
    }
    atomicAdd(&s_sum[o], sm);
    atomicAdd(&s_sq[o], sq);
  }
  __syncthreads();
  if (tid < CB) {
    atomicAdd(&wstat[WS_SUM1 + tid], s_sum[tid]);
    atomicAdd(&wstat[WS_SQ1  + tid], s_sq[tid]);
  }
}

// ---------------- K2/K4: fold BN stats into scale/shift ---------------------
__global__ void k_fin(const float* __restrict__ g, const float* __restrict__ b,
                      float* __restrict__ ws, int soff) {
  int c = threadIdx.x;
  float m   = ws[soff + c] * (1.f/NCNTF);
  float var = ws[soff + 64 + c] * (1.f/NCNTF) - m*m;
  float rstd = rsqrtf(var + 1e-5f);
  float sc = rstd * g[c];
  ws[soff + 128 + c] = sc;
  ws[soff + 192 + c] = b[c] - m * sc;
}

// ---------------- K3: MFMA temporal conv ------------------------------------
__global__ __launch_bounds__(256) void k3_mfma(
    const unsigned short* __restrict__ zb, const unsigned short* __restrict__ xtb,
    const float* __restrict__ bt, const float* __restrict__ ws,
    float* __restrict__ wstat, unsigned short* __restrict__ tco)
{
  __shared__ __align__(16) char ubuf[51456];      // yT (51200) / tc_lds (51456)
  __shared__ float s_sum[CB], s_sq[CB];
  int tid = threadIdx.x;
  int t0 = blockIdx.x * 8;                        // 38 blocks, t0 up to 296
  int n  = blockIdx.y;
  int l  = tid & 63;
  int mt = tid >> 6;
  int r  = l & 15;
  int g  = l >> 4;

  if (tid < CB) { s_sum[tid] = 0.f; s_sq[tid] = 0.f; }

  const unsigned short* wtp = (const unsigned short*)((const char*)ws + WS_WTP_BYTE);
  short8v afr[18];
  #pragma unroll
  for (int kt = 0; kt < 18; ++kt)
    afr[kt] = *(const short8v*)(wtp + ((size_t)((kt*4 + g)*64 + mt*16 + r)) * 8);

  {
    float sc1 = ws[WS_SC1 + l], sh1 = ws[WS_SH1 + l];
    int addr = n*480000 + (t0 - 4)*1600 + tid;    // linear: base + tv*64 + i
    int tv = tid >> 6;
    int vv = tv;
    int gt = t0 - 4;
    for (int it = 0; it < 100; ++it) {
      float y = 0.f;
      if (gt >= 0 && gt < TB) {
        float zv = bf2f(zb[addr]);
        float xv = bf2f(xtb[addr]);
        y = fmaxf(fmaf(zv, sc1, sh1) + xv, 0.f);
      }
      int wb = (tv << 7) + (((l << 1)) ^ ((tv & 7) << 4));
      *(unsigned short*)(ubuf + wb) = f2bf(y);
      addr += 256; tv += 4;
      vv += 4; if (vv >= 25) { vv -= 25; ++gt; }
    }
  }
  __syncthreads();

  f32x4 acc[13];
  #pragma unroll
  for (int ct = 0; ct < 13; ++ct) acc[ct] = (f32x4){0.f, 0.f, 0.f, 0.f};
  int delta12 = (r < 8) ? 12*2048 : -1024;        // col-tile 12 wrap (j_eff)
  #pragma unroll
  for (int kt = 0; kt < 18; ++kt) {
    int tap = kt >> 1, ih = kt & 1;
    int tv0 = r + 25*tap;
    int ab = (tv0 << 7) + (((ih << 6) + (g << 4)) ^ ((tv0 & 7) << 4));
    const char* pb = ubuf + ab;
    #pragma unroll
    for (int ct = 0; ct < 12; ++ct) {
      short8v b = *(const short8v*)(pb + ct*2048);
      acc[ct] = __builtin_amdgcn_mfma_f32_16x16x32_bf16(afr[kt], b, acc[ct], 0, 0, 0);
    }
    short8v b12 = *(const short8v*)(pb + delta12);
    acc[12] = __builtin_amdgcn_mfma_f32_16x16x32_bf16(afr[kt], b12, acc[12], 0, 0, 0);
  }
  __syncthreads();

  float* tcl = (float*)ubuf;
  #pragma unroll
  for (int ct = 0; ct < 13; ++ct) {
    int j = ct*16 + r;
    if (ct < 12 || r < 8) {
      int row0 = mt*16 + g*4;
      #pragma unroll
      for (int reg = 0; reg < 4; ++reg)
        tcl[(row0 + reg)*201 + j] = acc[ct][reg];
    }
  }
  __syncthreads();

  {
    int o = tid & 63, ch = tid >> 6;
    float bto = bt[o];
    int lim = 7500 - t0*25; if (lim > 200) lim = 200;
    int wsbase = n*480000 + t0*1600 + o;
    float sm = 0.f, sq = 0.f;
    for (int q = 0; q < 50; ++q) {
      int tv = ch*50 + q;
      if (tv < lim) {
        float val = tcl[o*201 + tv] + bto;
        tco[wsbase + tv*64] = f2bf(val);
        sm += val; sq += val*val;
      }
    }
    atomicAdd(&s_sum[o], sm);
    atomicAdd(&s_sq[o], sq);
  }
  __syncthreads();
  if (tid < CB) {
    atomicAdd(&wstat[WS_SUM2 + tid], s_sum[tid]);
    atomicAdd(&wstat[WS_SQ2  + tid], s_sq[tid]);
  }
}

// ---------------- K5: out = relu(bn2(tc) + x), full f32 d_out ---------------
__global__ __launch_bounds__(256) void k5_final(
    const float* __restrict__ x, const float* __restrict__ ws,
    const unsigned short* __restrict__ tc, float* __restrict__ out)
{
  __shared__ float tl5[200*65];
  int tid = threadIdx.x;
  int t0 = blockIdx.x * 8;
  int n  = blockIdx.y;
  int lim = 7500 - t0*25; if (lim > 200) lim = 200;
  int base = n*480000 + t0*1600;
  for (int idx = tid; idx < 200*64; idx += 256) {
    int tv = idx >> 6, o = idx & 63;
    if (tv < lim)
      tl5[tv*65 + o] = bf2f(tc[base + idx]);
  }
  __syncthreads();
  int w = tid >> 6, lane = tid & 63;
  for (int ol = 0; ol < 16; ++ol) {
    int o = w*16 + ol;
    float sc = ws[WS_SC2 + o], sh = ws[WS_SH2 + o];
    size_t gb = (size_t)(n*64 + o)*7500 + t0*25;
    #pragma unroll
    for (int c2 = 0; c2 < 4; ++c2) {
      int tv = c2*64 + lane;
      if (tv < lim) {
        float val = fmaf(tl5[tv*65 + o], sc, sh) + x[gb + tv];
        out[gb + tv] = fmaxf(val, 0.f);
      }
    }
  }
}

extern "C" void kernel_launch(void* const* d_in, const int* in_sizes, int n_in,
                              void* d_out, int out_size, void* d_ws, size_t ws_size,
                              hipStream_t stream) {
  const float* x  = (const float*)d_in[0];
  const float* A  = (const float*)d_in[1];
  const float* PA = (const float*)d_in[2];
  const float* Wd = (const float*)d_in[3];
  const float* bd = (const float*)d_in[4];
  const float* g1 = (const float*)d_in[5];
  const float* b1 = (const float*)d_in[6];
  const float* Wt = (const float*)d_in[7];
  const float* bt = (const float*)d_in[8];
  const float* g2 = (const float*)d_in[9];
  const float* b2 = (const float*)d_in[10];

  float* ws = (float*)d_ws;
  unsigned short* zbuf = (unsigned short*)d_out;            // z' scratch
  unsigned short* xtb  = (unsigned short*)d_out + ZP_ELEMS; // xT scratch
  unsigned short* tc   = (unsigned short*)((char*)d_ws + WS_TC_BYTE);
  float* out = (float*)d_out;

  k0_prep<<<dim3(64), dim3(256), 0, stream>>>(A, PA, Wd, Wt, ws);
  k_xt<<<dim3(38, 64), dim3(256), 0, stream>>>(x, xtb);
  k1_gcn<<<dim3(75, 64), dim3(256), 0, stream>>>(x, bd, ws, ws, zbuf);
  k_fin<<<dim3(1), dim3(64), 0, stream>>>(g1, b1, ws, 0);
  k3_mfma<<<dim3(38, 64), dim3(256), 0, stream>>>(zbuf, xtb, bt, ws, ws, tc);
  k_fin<<<dim3(1), dim3(64), 0, stream>>>(g2, b2, ws, 256);
  k5_final<<<dim3(38, 64), dim3(256), 0, stream>>>(x, ws, tc, out);
}

// Round 10
// 521.467 us; speedup vs baseline: 4.8448x; 1.2483x over previous
//
#include <hip/hip_runtime.h>

#define NB 64
#define CB 64
#define TB 300
#define VB 25
#define SB 3
#define KB 9
#define NCNTF 480000.0f  // N*T*V per channel

// ws float offsets (stats block)
#define WS_SUM1 0
#define WS_SQ1  64
#define WS_SC1  128
#define WS_SH1  192
#define WS_SUM2 256
#define WS_SQ2  320
#define WS_SC2  384
#define WS_SH2  448
// ws byte offsets
#define WS_WTP_BYTE 2048              // k3 A-frags (32x32): 36*2*64*8 bf16 = 73728 B
#define WS_AQP_BYTE 75776             // k1 stage1 A-frags (Aq hi/lo): 12*64*8 bf16
#define WS_WDP_BYTE 88064             // k1 stage2 A-frags (Wd hi/lo): 48*64*8 bf16
#define WS_TC_BYTE  262144            // tc bf16 [n][t][v][o]: 61.44 MB
// d_out scratch layout (ushort elements)
#define ZP_ELEMS    30720000          // z' bf16 [n][t][v][c] at d_out[0]
                                      // xT bf16 [n][t][v][c] at d_out[ZP_ELEMS]

typedef __attribute__((ext_vector_type(8))) short short8v;
typedef __attribute__((ext_vector_type(4))) float f32x4;
typedef __attribute__((ext_vector_type(16))) float f32x16;

__device__ __forceinline__ float bf2f(unsigned short u) {
  unsigned int v = ((unsigned int)u) << 16;
  float f; __builtin_memcpy(&f, &v, 4); return f;
}
__device__ __forceinline__ unsigned short f2bf(float f) {
  unsigned int x; __builtin_memcpy(&x, &f, 4);
  x += 0x7fffu + ((x >> 16) & 1u);
  return (unsigned short)(x >> 16);
}

// ---------------- K0: prep (pack Wt 32x32-frags, Aq hi/lo, Wd hi/lo) --------
__global__ void k0_prep(const float* __restrict__ A, const float* __restrict__ PA,
                        const float* __restrict__ Wd, const float* __restrict__ Wt,
                        float* __restrict__ ws) {
  int gid = blockIdx.x * 256 + threadIdx.x;
  int gs  = gridDim.x * 256;
  for (int i = gid; i < 512; i += gs) ws[i] = 0.f;
  // WtP32[kt][mt][l][j] = bf16(Wt[o=mt*32+(l&31)][i=(kt&3)*16+(l>>5)*8+j][tap=kt>>2])
  unsigned short* wtp = (unsigned short*)((char*)ws + WS_WTP_BYTE);
  for (int idx = gid; idx < 36*2*64*8; idx += gs) {
    int j = idx & 7, li = (idx >> 3) & 63, mt = (idx >> 9) & 1, kt = idx >> 10;
    int o = mt*32 + (li & 31);
    int i = (kt & 3)*16 + (li >> 5)*8 + j;
    int tap = kt >> 2;
    wtp[idx] = f2bf(Wt[(o*64 + i)*9 + tap]);
  }
  // AqP: frag f = s*4 + wt*2 + h; lane l; elem j: A[row=w][k=v] hi/lo split
  unsigned short* aqp = (unsigned short*)((char*)ws + WS_AQP_BYTE);
  for (int idx = gid; idx < 12*64*8; idx += gs) {
    int j = idx & 7, l = (idx >> 3) & 63, fi = idx >> 9;
    int h = fi & 1, wt = (fi >> 1) & 1, s = fi >> 2;
    int v = (l >> 4)*8 + j, w = wt*16 + (l & 15);
    unsigned short out = 0;
    if (v < VB && w < VB) {
      int ai = (s*VB + v)*VB + w;
      float a = A[ai] + PA[ai];
      float q = truncf(a * 1024.f);
      q = fminf(fmaxf(q, -32768.f), 32768.f);
      float aq = q * (1.f/1024.f);
      unsigned short hi = f2bf(aq);
      out = h ? f2bf(aq - bf2f(hi)) : hi;
    }
    aqp[idx] = out;
  }
  // WdP: frag fi = (h*6+kt)*4 + mt; A[row=o][k=s*64+c] hi/lo split
  unsigned short* wdp = (unsigned short*)((char*)ws + WS_WDP_BYTE);
  for (int idx = gid; idx < 48*64*8; idx += gs) {
    int j = idx & 7, l = (idx >> 3) & 63, fi = idx >> 9;
    int mt = fi & 3, q2 = fi >> 2;
    int kt = q2 % 6, h = q2 / 6;
    int k = kt*32 + (l >> 4)*8 + j;
    int s = k >> 6, c = k & 63, o = mt*16 + (l & 15);
    float wv = Wd[(s*64 + o)*64 + c];
    unsigned short hi = f2bf(wv);
    wdp[idx] = h ? f2bf(wv - bf2f(hi)) : hi;
  }
}

// ---------------- K1: MFMA GCN  z' = sum_s Wd[s] @ x @ Aq[s] + bias ---------
// also emits xT bf16 [n][t][v][c] (fused former k_xt)
__global__ __launch_bounds__(256) void k1_gcn(
    const float* __restrict__ x, const float* __restrict__ bd,
    const float* __restrict__ ws, float* __restrict__ wstat,
    unsigned short* __restrict__ zout, unsigned short* __restrict__ xtout)
{
  __shared__ __align__(16) char k1lds[33792 + 43008];
  __shared__ float s_sum[CB], s_sq[CB];
  float* xls = (float*)k1lds;            // [4t][64c][33v] f32
  char*  xab = k1lds + 33792;            // xa bf16 [112 rows][384 B] swizzled
  float* zg  = (float*)k1lds;            // reuse: [100 tw][65 o] f32
  int tid = threadIdx.x;
  int t0 = blockIdx.x * 4;               // 75*4 == 300 exact
  int n  = blockIdx.y;
  int wv = tid >> 6, l = tid & 63, r = l & 15, g = l >> 4;

  if (tid < CB) { s_sum[tid] = 0.f; s_sq[tid] = 0.f; }
  // stage x tile f32: [tl][c][33] (stride 33 -> conflict-free)
  for (int idx = tid; idx < 6400; idx += 256) {
    int c = idx / 100, rem = idx - c*100, tl = rem / 25, v = rem - tl*25;
    xls[(tl*64 + c)*33 + v] = x[((size_t)(n*64 + c)*300 + t0 + tl)*25 + v];
  }
  for (int idx = tid; idx < 1792; idx += 256) {   // zero pad v=25..31
    int tl = idx / 448, rem = idx - tl*448, c = rem / 7, v = 25 + rem - c*7;
    xls[(tl*64 + c)*33 + v] = 0.f;
  }
  __syncthreads();

  // fused xT emission (coalesced [tv][c] bf16 store)
  for (int idx = tid; idx < 6400; idx += 256) {
    int tv = idx >> 6, c = idx & 63;
    int tl = tv / 25, v = tv - tl*25;
    xtout[n*480000 + t0*1600 + idx] = f2bf(xls[(tl*64 + c)*33 + v]);
  }

  const unsigned short* aqp = (const unsigned short*)((const char*)ws + WS_AQP_BYTE);
  const unsigned short* wdp = (const unsigned short*)((const char*)ws + WS_WDP_BYTE);

  // B1 fragments: B[k=v][col=c] from xls (wave wv owns t=wv)
  short8v b1[4];
  #pragma unroll
  for (int ct = 0; ct < 4; ++ct) {
    int c = ct*16 + r;
    #pragma unroll
    for (int j = 0; j < 8; ++j)
      b1[ct][j] = (short)f2bf(xls[(wv*64 + c)*33 + g*8 + j]);
  }

  // ---- stage1: per s, xa[w][c] = sum_v Aq[s][v][w] * x[c][v] ----
  for (int s = 0; s < SB; ++s) {
    short8v a1[4];
    #pragma unroll
    for (int q = 0; q < 4; ++q)
      a1[q] = *(const short8v*)(aqp + ((s*4 + q)*64 + l)*8);
    f32x4 acc1[8];
    #pragma unroll
    for (int i = 0; i < 8; ++i) acc1[i] = (f32x4){0.f,0.f,0.f,0.f};
    #pragma unroll
    for (int wt = 0; wt < 2; ++wt)
      #pragma unroll
      for (int ct = 0; ct < 4; ++ct) {
        acc1[wt*4+ct] = __builtin_amdgcn_mfma_f32_16x16x32_bf16(a1[wt*2+0], b1[ct], acc1[wt*4+ct], 0,0,0);
        acc1[wt*4+ct] = __builtin_amdgcn_mfma_f32_16x16x32_bf16(a1[wt*2+1], b1[ct], acc1[wt*4+ct], 0,0,0);
      }
    // C -> xa LDS (bf16, XOR-swizzled 16B granules)
    #pragma unroll
    for (int wt = 0; wt < 2; ++wt)
      #pragma unroll
      for (int ct = 0; ct < 4; ++ct)
        #pragma unroll
        for (int reg = 0; reg < 4; ++reg) {
          int w = wt*16 + g*4 + reg;
          if (w < VB) {
            int row = wv*25 + w, c = ct*16 + r;
            int bir = (s*128 + c*2) ^ ((row & 7) << 4);
            *(unsigned short*)(xab + row*384 + bir) = f2bf(acc1[wt*4+ct][reg]);
          }
        }
  }
  __syncthreads();

  // ---- stage2: z[o][tw] = sum_{s,c} Wd * xa, K=192 ----
  short8v a2[12];
  #pragma unroll
  for (int h = 0; h < 2; ++h)
    #pragma unroll
    for (int kt = 0; kt < 6; ++kt)
      a2[h*6+kt] = *(const short8v*)(wdp + (((h*6 + kt)*4 + wv)*64 + l)*8);
  f32x4 acc2[7];
  #pragma unroll
  for (int i = 0; i < 7; ++i) acc2[i] = (f32x4){0.f,0.f,0.f,0.f};
  for (int kt = 0; kt < 6; ++kt) {
    #pragma unroll
    for (int ct = 0; ct < 7; ++ct) {
      int row = ct*16 + r;
      int bir = (kt*64 + g*16) ^ ((r & 7) << 4);
      short8v b = *(const short8v*)(xab + row*384 + bir);
      acc2[ct] = __builtin_amdgcn_mfma_f32_16x16x32_bf16(a2[kt],   b, acc2[ct], 0,0,0);
      acc2[ct] = __builtin_amdgcn_mfma_f32_16x16x32_bf16(a2[6+kt], b, acc2[ct], 0,0,0);
    }
  }
  // C -> zg (reuses xls region; all xls reads finished pre-barrier)
  #pragma unroll
  for (int ct = 0; ct < 7; ++ct) {
    int tw = ct*16 + r;
    if (tw < 100) {
      #pragma unroll
      for (int reg = 0; reg < 4; ++reg)
        zg[tw*65 + wv*16 + g*4 + reg] = acc2[ct][reg];
    }
  }
  __syncthreads();

  // epilogue: bias + BN1 stats + coalesced bf16 z' store ([n][t][v][c])
  {
    int o = tid & 63, chunk = tid >> 6;
    float bsum = bd[o] + bd[CB + o] + bd[2*CB + o];
    unsigned short* zr = zout + n*480000 + t0*1600 + o;
    float sm = 0.f, sq = 0.f;
    for (int q = 0; q < 25; ++q) {
      int tw = chunk*25 + q;
      float val = zg[tw*65 + o] + bsum;
      zr[tw*64] = f2bf(val);
      sm += val; sq += val*val;
    }
    atomicAdd(&s_sum[o], sm);
    atomicAdd(&s_sq[o], sq);
  }
  __syncthreads();
  if (tid < CB) {
    atomicAdd(&wstat[WS_SUM1 + tid], s_sum[tid]);
    atomicAdd(&wstat[WS_SQ1  + tid], s_sq[tid]);
  }
}

// ---------------- K2/K4: fold BN stats into scale/shift ---------------------
__global__ void k_fin(const float* __restrict__ g, const float* __restrict__ b,
                      float* __restrict__ ws, int soff) {
  int c = threadIdx.x;
  float m   = ws[soff + c] * (1.f/NCNTF);
  float var = ws[soff + 64 + c] * (1.f/NCNTF) - m*m;
  float rstd = rsqrtf(var + 1e-5f);
  float sc = rstd * g[c];
  ws[soff + 128 + c] = sc;
  ws[soff + 192 + c] = b[c] - m * sc;
}

// ---------------- K3: MFMA 32x32x16 temporal conv ---------------------------
__global__ __launch_bounds__(256) void k3_mfma(
    const unsigned short* __restrict__ zb, const unsigned short* __restrict__ xtb,
    const float* __restrict__ bt, const float* __restrict__ ws,
    float* __restrict__ wstat, unsigned short* __restrict__ tco)
{
  __shared__ __align__(16) char ubuf[51456];      // yT (51200) / tc_lds (51456)
  __shared__ float s_sum[CB], s_sq[CB];
  int tid = threadIdx.x;
  int t0 = blockIdx.x * 8;                        // 38 blocks
  int n  = blockIdx.y;
  int wv = tid >> 6, l = tid & 63;
  int lane31 = l & 31, lh = l >> 5;
  int mt = wv & 1, cth = wv >> 1;

  if (tid < CB) { s_sum[tid] = 0.f; s_sq[tid] = 0.f; }

  // --- stage yT: 400 tv-rows x 64 i (bf16), swizzled, ushort4-vectorized ---
  {
    int c0 = (tid & 15) * 4;
    int rowsel = tid >> 4;                        // 0..15
    float4 sc4 = *(const float4*)(ws + WS_SC1 + c0);
    float4 sh4 = *(const float4*)(ws + WS_SH1 + c0);
    for (int it = 0; it < 25; ++it) {
      int tv = it*16 + rowsel;
      int gt = t0 - 4 + tv/25;
      ushort4 yv = {0,0,0,0};
      if (gt >= 0 && gt < TB) {
        int addr = n*480000 + (t0-4)*1600 + tv*64 + c0;
        ushort4 z4 = *(const ushort4*)(zb + addr);
        ushort4 x4 = *(const ushort4*)(xtb + addr);
        yv.x = f2bf(fmaxf(fmaf(bf2f(z4.x), sc4.x, sh4.x) + bf2f(x4.x), 0.f));
        yv.y = f2bf(fmaxf(fmaf(bf2f(z4.y), sc4.y, sh4.y) + bf2f(x4.y), 0.f));
        yv.z = f2bf(fmaxf(fmaf(bf2f(z4.z), sc4.z, sh4.z) + bf2f(x4.z), 0.f));
        yv.w = f2bf(fmaxf(fmaf(bf2f(z4.w), sc4.w, sh4.w) + bf2f(x4.w), 0.f));
      }
      int wb = (tv << 7) + ((c0*2) ^ ((tv & 7) << 4));
      *(ushort4*)(ubuf + wb) = yv;
    }
  }
  __syncthreads();

  // --- MFMA main loop: 36 K-tiles (two phases of 18), 4 col-tiles/wave ---
  const unsigned short* wtp = (const unsigned short*)((const char*)ws + WS_WTP_BYTE);
  f32x16 acc0 = {0.f}, acc1 = {0.f}, acc2 = {0.f}, acc3 = {0.f};
  #pragma unroll
  for (int i = 0; i < 16; ++i) { acc0[i]=0.f; acc1[i]=0.f; acc2[i]=0.f; acc3[i]=0.f; }

  for (int ph = 0; ph < 2; ++ph) {
    short8v af[18];
    #pragma unroll
    for (int q = 0; q < 18; ++q)
      af[q] = *(const short8v*)(wtp + (((ph*18 + q)*2 + mt)*64 + l)*8);
    #pragma unroll
    for (int q = 0; q < 18; ++q) {
      int kt = ph*18 + q;
      int tap = kt >> 2;
      int ioff2 = ((kt & 3)*16 + lh*8) * 2;
#define DOCT(ACC, CTL) { \
      int col = (cth*4 + (CTL))*32 + lane31; \
      int tvB = (col < 200 ? col : 199) + 25*tap; \
      int ab = (tvB << 7) + (ioff2 ^ ((tvB & 7) << 4)); \
      short8v b = *(const short8v*)(ubuf + ab); \
      ACC = __builtin_amdgcn_mfma_f32_32x32x16_bf16(af[q], b, ACC, 0, 0, 0); }
      DOCT(acc0, 0) DOCT(acc1, 1) DOCT(acc2, 2) DOCT(acc3, 3)
#undef DOCT
    }
  }
  __syncthreads();

  // --- C-frags -> LDS [o][201] f32 ---
  float* tcl = (float*)ubuf;
  {
    int rowbase = mt*32 + 4*lh;
#define STCT(ACC, CTL) { \
    int col = (cth*4 + (CTL))*32 + lane31; \
    if (col < 201) { \
      _Pragma("unroll") \
      for (int rg = 0; rg < 16; ++rg) { \
        int o = rowbase + (rg & 3) + 8*(rg >> 2); \
        tcl[o*201 + col] = ACC[rg]; } } }
    STCT(acc0, 0) STCT(acc1, 1) STCT(acc2, 2) STCT(acc3, 3)
#undef STCT
  }
  __syncthreads();

  // --- bias + BN2 stats + bf16 store ([n][t][v][o]) ---
  {
    int o = tid & 63, ch = tid >> 6;
    float bto = bt[o];
    int lim = 7500 - t0*25; if (lim > 200) lim = 200;
    int wsbase = n*480000 + t0*1600 + o;
    float sm = 0.f, sq = 0.f;
    for (int q = 0; q < 50; ++q) {
      int tv = ch*50 + q;
      if (tv < lim) {
        float val = tcl[o*201 + tv] + bto;
        tco[wsbase + tv*64] = f2bf(val);
        sm += val; sq += val*val;
      }
    }
    atomicAdd(&s_sum[o], sm);
    atomicAdd(&s_sq[o], sq);
  }
  __syncthreads();
  if (tid < CB) {
    atomicAdd(&wstat[WS_SUM2 + tid], s_sum[tid]);
    atomicAdd(&wstat[WS_SQ2  + tid], s_sq[tid]);
  }
}

// ---------------- K5: out = relu(bn2(tc) + x), full f32 d_out ---------------
__global__ __launch_bounds__(256) void k5_final(
    const float* __restrict__ x, const float* __restrict__ ws,
    const unsigned short* __restrict__ tc, float* __restrict__ out)
{
  __shared__ float tl5[200*65];
  int tid = threadIdx.x;
  int t0 = blockIdx.x * 8;
  int n  = blockIdx.y;
  int lim = 7500 - t0*25; if (lim > 200) lim = 200;
  int base = n*480000 + t0*1600;
  for (int idx = tid; idx < 200*64; idx += 256) {
    int tv = idx >> 6, o = idx & 63;
    if (tv < lim)
      tl5[tv*65 + o] = bf2f(tc[base + idx]);
  }
  __syncthreads();
  int w = tid >> 6, lane = tid & 63;
  for (int ol = 0; ol < 16; ++ol) {
    int o = w*16 + ol;
    float sc = ws[WS_SC2 + o], sh = ws[WS_SH2 + o];
    size_t gb = (size_t)(n*64 + o)*7500 + t0*25;
    #pragma unroll
    for (int c2 = 0; c2 < 4; ++c2) {
      int tv = c2*64 + lane;
      if (tv < lim) {
        float val = fmaf(tl5[tv*65 + o], sc, sh) + x[gb + tv];
        out[gb + tv] = fmaxf(val, 0.f);
      }
    }
  }
}

extern "C" void kernel_launch(void* const* d_in, const int* in_sizes, int n_in,
                              void* d_out, int out_size, void* d_ws, size_t ws_size,
                              hipStream_t stream) {
  const float* x  = (const float*)d_in[0];
  const float* A  = (const float*)d_in[1];
  const float* PA = (const float*)d_in[2];
  const float* Wd = (const float*)d_in[3];
  const float* bd = (const float*)d_in[4];
  const float* g1 = (const float*)d_in[5];
  const float* b1 = (const float*)d_in[6];
  const float* Wt = (const float*)d_in[7];
  const float* bt = (const float*)d_in[8];
  const float* g2 = (const float*)d_in[9];
  const float* b2 = (const float*)d_in[10];

  float* ws = (float*)d_ws;
  unsigned short* zbuf = (unsigned short*)d_out;            // z' scratch
  unsigned short* xtb  = (unsigned short*)d_out + ZP_ELEMS; // xT scratch
  unsigned short* tc   = (unsigned short*)((char*)d_ws + WS_TC_BYTE);
  float* out = (float*)d_out;

  k0_prep<<<dim3(64), dim3(256), 0, stream>>>(A, PA, Wd, Wt, ws);
  k1_gcn<<<dim3(75, 64), dim3(256), 0, stream>>>(x, bd, ws, ws, zbuf, xtb);
  k_fin<<<dim3(1), dim3(64), 0, stream>>>(g1, b1, ws, 0);
  k3_mfma<<<dim3(38, 64), dim3(256), 0, stream>>>(zbuf, xtb, bt, ws, ws, tc);
  k_fin<<<dim3(1), dim3(64), 0, stream>>>(g2, b2, ws, 256);
  k5_final<<<dim3(38, 64), dim3(256), 0, stream>>>(x, ws, tc, out);
}

// Round 12
// 513.848 us; speedup vs baseline: 4.9166x; 1.0148x over previous
//
#include <hip/hip_runtime.h>

#define NB 64
#define CB 64
#define TB 300
#define VB 25
#define SB 3
#define KB 9
#define NCNTF 480000.0f  // N*T*V per channel

// ws float offsets (stats block)
#define WS_SUM1 0
#define WS_SQ1  64
#define WS_SC1  128
#define WS_SH1  192
#define WS_SUM2 256
#define WS_SQ2  320
#define WS_SC2  384
#define WS_SH2  448
// ws byte offsets
#define WS_WTP_BYTE 2048              // k3 A-frags (32x32): 36*2*64*8 bf16 = 73728 B
#define WS_AQP_BYTE 75776             // k1 stage1 A-frags (Aq hi/lo): 12*64*8 bf16
#define WS_WDP_BYTE 88064             // k1 stage2 A-frags (Wd hi/lo): 48*64*8 bf16
#define WS_TC_BYTE  262144            // tc bf16 [n][t][v][o]: 61.44 MB
// d_out scratch layout (ushort elements)
#define ZP_ELEMS    30720000          // z' bf16 [n][t][v][c] at d_out[0]
                                      // xT bf16 [n][t][v][c] at d_out[ZP_ELEMS]

typedef __attribute__((ext_vector_type(8))) short short8v;
typedef __attribute__((ext_vector_type(4))) float f32x4;
typedef __attribute__((ext_vector_type(16))) float f32x16;

__device__ __forceinline__ float bf2f(unsigned short u) {
  unsigned int v = ((unsigned int)u) << 16;
  float f; __builtin_memcpy(&f, &v, 4); return f;
}
__device__ __forceinline__ unsigned short f2bf(float f) {
  unsigned int x; __builtin_memcpy(&x, &f, 4);
  x += 0x7fffu + ((x >> 16) & 1u);
  return (unsigned short)(x >> 16);
}

// ---------------- K0: prep (pack Wt 32x32-frags, Aq hi/lo, Wd hi/lo) --------
__global__ void k0_prep(const float* __restrict__ A, const float* __restrict__ PA,
                        const float* __restrict__ Wd, const float* __restrict__ Wt,
                        float* __restrict__ ws) {
  int gid = blockIdx.x * 256 + threadIdx.x;
  int gs  = gridDim.x * 256;
  for (int i = gid; i < 512; i += gs) ws[i] = 0.f;
  // WtP32[kt][mt][l][j] = bf16(Wt[o=mt*32+(l&31)][i=(kt&3)*16+(l>>5)*8+j][tap=kt>>2])
  unsigned short* wtp = (unsigned short*)((char*)ws + WS_WTP_BYTE);
  for (int idx = gid; idx < 36*2*64*8; idx += gs) {
    int j = idx & 7, li = (idx >> 3) & 63, mt = (idx >> 9) & 1, kt = idx >> 10;
    int o = mt*32 + (li & 31);
    int i = (kt & 3)*16 + (li >> 5)*8 + j;
    int tap = kt >> 2;
    wtp[idx] = f2bf(Wt[(o*64 + i)*9 + tap]);
  }
  // AqP: frag f = s*4 + wt*2 + h; lane l; elem j: A[row=w][k=v] hi/lo split
  unsigned short* aqp = (unsigned short*)((char*)ws + WS_AQP_BYTE);
  for (int idx = gid; idx < 12*64*8; idx += gs) {
    int j = idx & 7, l = (idx >> 3) & 63, fi = idx >> 9;
    int h = fi & 1, wt = (fi >> 1) & 1, s = fi >> 2;
    int v = (l >> 4)*8 + j, w = wt*16 + (l & 15);
    unsigned short out = 0;
    if (v < VB && w < VB) {
      int ai = (s*VB + v)*VB + w;
      float a = A[ai] + PA[ai];
      float q = truncf(a * 1024.f);
      q = fminf(fmaxf(q, -32768.f), 32768.f);
      float aq = q * (1.f/1024.f);
      unsigned short hi = f2bf(aq);
      out = h ? f2bf(aq - bf2f(hi)) : hi;
    }
    aqp[idx] = out;
  }
  // WdP: frag fi = (h*6+kt)*4 + mt; A[row=o][k=s*64+c] hi/lo split
  unsigned short* wdp = (unsigned short*)((char*)ws + WS_WDP_BYTE);
  for (int idx = gid; idx < 48*64*8; idx += gs) {
    int j = idx & 7, l = (idx >> 3) & 63, fi = idx >> 9;
    int mt = fi & 3, q2 = fi >> 2;
    int kt = q2 % 6, h = q2 / 6;
    int k = kt*32 + (l >> 4)*8 + j;
    int s = k >> 6, c = k & 63, o = mt*16 + (l & 15);
    float wv = Wd[(s*64 + o)*64 + c];
    unsigned short hi = f2bf(wv);
    wdp[idx] = h ? f2bf(wv - bf2f(hi)) : hi;
  }
}

// ---------------- K1: MFMA GCN  z' = sum_s Wd[s] @ x @ Aq[s] + bias ---------
// 512 threads / 8 waves; x staged as bf16; also emits xT (fused k_xt)
__global__ __launch_bounds__(512) void k1_gcn(
    const float* __restrict__ x, const float* __restrict__ bd,
    const float* __restrict__ ws, float* __restrict__ wstat,
    unsigned short* __restrict__ zout, unsigned short* __restrict__ xtout)
{
  __shared__ __align__(16) char k1lds[63488];
  __shared__ float s_sum[CB], s_sq[CB];
  unsigned short* xls = (unsigned short*)k1lds;   // [4t][64c][40v] bf16
  char*  xab = k1lds + 20480;                     // xa bf16 [112 rows][384 B] swizzled
  float* zg  = (float*)k1lds;                     // reuse after barrier: [100 tw][65 o]
  int tid = threadIdx.x;
  int t0 = blockIdx.x * 4;               // 75*4 == 300 exact
  int n  = blockIdx.y;
  int wv = tid >> 6, l = tid & 63, r = l & 15, g = l >> 4;

  if (tid < CB) { s_sum[tid] = 0.f; s_sq[tid] = 0.f; }
  // stage x tile as bf16: [tl][c][40]
  for (int idx = tid; idx < 6400; idx += 512) {
    int c = idx / 100, rem = idx - c*100, tl = rem / 25, v = rem - tl*25;
    xls[(tl*64 + c)*40 + v] = f2bf(x[((size_t)(n*64 + c)*300 + t0 + tl)*25 + v]);
  }
  for (int idx = tid; idx < 1792; idx += 512) {   // zero pad v=25..31
    int tl = idx / 448, rem = idx - tl*448, c = rem / 7, v = 25 + rem - c*7;
    xls[(tl*64 + c)*40 + v] = 0;
  }
  __syncthreads();

  // fused xT emission (coalesced [tv][c] bf16 store)
  for (int idx = tid; idx < 6400; idx += 512) {
    int tv = idx >> 6, c = idx & 63;
    int tl = tv / 25, v = tv - tl*25;
    xtout[n*480000 + t0*1600 + idx] = xls[(tl*64 + c)*40 + v];
  }

  const unsigned short* aqp = (const unsigned short*)((const char*)ws + WS_AQP_BYTE);
  const unsigned short* wdp = (const unsigned short*)((const char*)ws + WS_WDP_BYTE);

  // ---- stage1: 24 (s,t,wt) units, 3 per wave ----
  #pragma unroll
  for (int q = 0; q < 3; ++q) {
    int u = wv*3 + q;
    int s = u >> 3, rem = u & 7, t = rem >> 1, wt = rem & 1;
    short8v a1h = *(const short8v*)(aqp + ((s*4 + wt*2 + 0)*64 + l)*8);
    short8v a1l = *(const short8v*)(aqp + ((s*4 + wt*2 + 1)*64 + l)*8);
    f32x4 acc1[4];
    #pragma unroll
    for (int ct = 0; ct < 4; ++ct) acc1[ct] = (f32x4){0.f,0.f,0.f,0.f};
    #pragma unroll
    for (int ct = 0; ct < 4; ++ct) {
      int c = ct*16 + r;
      short8v b = *(const short8v*)(xls + (t*64 + c)*40 + g*8);
      acc1[ct] = __builtin_amdgcn_mfma_f32_16x16x32_bf16(a1h, b, acc1[ct], 0,0,0);
      acc1[ct] = __builtin_amdgcn_mfma_f32_16x16x32_bf16(a1l, b, acc1[ct], 0,0,0);
    }
    #pragma unroll
    for (int ct = 0; ct < 4; ++ct)
      #pragma unroll
      for (int reg = 0; reg < 4; ++reg) {
        int w = wt*16 + g*4 + reg;
        if (w < VB) {
          int row = t*25 + w, c = ct*16 + r;
          int bir = (s*128 + c*2) ^ ((row & 7) << 4);
          *(unsigned short*)(xab + row*384 + bir) = f2bf(acc1[ct][reg]);
        }
      }
  }
  __syncthreads();

  // ---- stage2: z[o][tw], K=192; wave = (o-quarter mt2, tw-half th2) ----
  int mt2 = wv & 3, th2 = wv >> 2;
  short8v a2[12];
  #pragma unroll
  for (int h = 0; h < 2; ++h)
    #pragma unroll
    for (int kt = 0; kt < 6; ++kt)
      a2[h*6+kt] = *(const short8v*)(wdp + (((h*6 + kt)*4 + mt2)*64 + l)*8);
  f32x4 acc2[4];
  #pragma unroll
  for (int i = 0; i < 4; ++i) acc2[i] = (f32x4){0.f,0.f,0.f,0.f};
  for (int kt = 0; kt < 6; ++kt) {
    #pragma unroll
    for (int ctl = 0; ctl < 4; ++ctl) {
      int rowb = (th2*4 + ctl)*16 + r;
      if (rowb > 111) rowb = 111;              // clamp: tw>=112 discarded anyway
      int bir = (kt*64 + g*16) ^ ((r & 7) << 4);
      short8v b = *(const short8v*)(xab + rowb*384 + bir);
      acc2[ctl] = __builtin_amdgcn_mfma_f32_16x16x32_bf16(a2[kt],   b, acc2[ctl], 0,0,0);
      acc2[ctl] = __builtin_amdgcn_mfma_f32_16x16x32_bf16(a2[6+kt], b, acc2[ctl], 0,0,0);
    }
  }
  __syncthreads();   // zg overlaps xls+xab: wait for all xab reads
  #pragma unroll
  for (int ctl = 0; ctl < 4; ++ctl) {
    int tw = (th2*4 + ctl)*16 + r;
    if (tw < 100) {
      #pragma unroll
      for (int reg = 0; reg < 4; ++reg)
        zg[tw*65 + mt2*16 + g*4 + reg] = acc2[ctl][reg];
    }
  }
  __syncthreads();

  // epilogue: bias + BN1 stats + coalesced bf16 z' store ([n][t][v][c])
  {
    int o = tid & 63, chunk = tid >> 6;
    float bsum = bd[o] + bd[CB + o] + bd[2*CB + o];
    unsigned short* zr = zout + n*480000 + t0*1600 + o;
    float sm = 0.f, sq = 0.f;
    for (int qq = 0; qq < 13; ++qq) {
      int tw = chunk*13 + qq;
      if (tw < 100) {
        float val = zg[tw*65 + o] + bsum;
        zr[tw*64] = f2bf(val);
        sm += val; sq += val*val;
      }
    }
    atomicAdd(&s_sum[o], sm);
    atomicAdd(&s_sq[o], sq);
  }
  __syncthreads();
  if (tid < CB) {
    atomicAdd(&wstat[WS_SUM1 + tid], s_sum[tid]);
    atomicAdd(&wstat[WS_SQ1  + tid], s_sq[tid]);
  }
}

// ---------------- K2/K4: fold BN stats into scale/shift ---------------------
__global__ void k_fin(const float* __restrict__ g, const float* __restrict__ b,
                      float* __restrict__ ws, int soff) {
  int c = threadIdx.x;
  float m   = ws[soff + c] * (1.f/NCNTF);
  float var = ws[soff + 64 + c] * (1.f/NCNTF) - m*m;
  float rstd = rsqrtf(var + 1e-5f);
  float sc = rstd * g[c];
  ws[soff + 128 + c] = sc;
  ws[soff + 192 + c] = b[c] - m * sc;
}

// ---------------- K3: MFMA 32x32x16 temporal conv ---------------------------
__global__ __launch_bounds__(256) void k3_mfma(
    const unsigned short* __restrict__ zb, const unsigned short* __restrict__ xtb,
    const float* __restrict__ bt, const float* __restrict__ ws,
    float* __restrict__ wstat, unsigned short* __restrict__ tco)
{
  __shared__ __align__(16) char ubuf[51456];      // yT (51200) / tc_lds (51456)
  __shared__ float s_sum[CB], s_sq[CB];
  int tid = threadIdx.x;
  int t0 = blockIdx.x * 8;                        // 38 blocks
  int n  = blockIdx.y;
  int wv = tid >> 6, l = tid & 63;
  int lane31 = l & 31, lh = l >> 5;
  int mt = wv & 1, cth = wv >> 1;

  if (tid < CB) { s_sum[tid] = 0.f; s_sq[tid] = 0.f; }

  // --- stage yT: 400 tv-rows x 64 i (bf16), swizzled, ushort4-vectorized ---
  {
    int c0 = (tid & 15) * 4;
    int rowsel = tid >> 4;                        // 0..15
    float4 sc4 = *(const float4*)(ws + WS_SC1 + c0);
    float4 sh4 = *(const float4*)(ws + WS_SH1 + c0);
    for (int it = 0; it < 25; ++it) {
      int tv = it*16 + rowsel;
      int gt = t0 - 4 + tv/25;
      ushort4 yv = {0,0,0,0};
      if (gt >= 0 && gt < TB) {
        int addr = n*480000 + (t0-4)*1600 + tv*64 + c0;
        ushort4 z4 = *(const ushort4*)(zb + addr);
        ushort4 x4 = *(const ushort4*)(xtb + addr);
        yv.x = f2bf(fmaxf(fmaf(bf2f(z4.x), sc4.x, sh4.x) + bf2f(x4.x), 0.f));
        yv.y = f2bf(fmaxf(fmaf(bf2f(z4.y), sc4.y, sh4.y) + bf2f(x4.y), 0.f));
        yv.z = f2bf(fmaxf(fmaf(bf2f(z4.z), sc4.z, sh4.z) + bf2f(x4.z), 0.f));
        yv.w = f2bf(fmaxf(fmaf(bf2f(z4.w), sc4.w, sh4.w) + bf2f(x4.w), 0.f));
      }
      int wb = (tv << 7) + ((c0*2) ^ ((tv & 7) << 4));
      *(ushort4*)(ubuf + wb) = yv;
    }
  }
  __syncthreads();

  // --- MFMA main loop: 36 K-tiles (two phases of 18), 4 col-tiles/wave ---
  const unsigned short* wtp = (const unsigned short*)((const char*)ws + WS_WTP_BYTE);
  f32x16 acc0, acc1, acc2, acc3;
  #pragma unroll
  for (int i = 0; i < 16; ++i) { acc0[i]=0.f; acc1[i]=0.f; acc2[i]=0.f; acc3[i]=0.f; }

  for (int ph = 0; ph < 2; ++ph) {
    short8v af[18];
    #pragma unroll
    for (int q = 0; q < 18; ++q)
      af[q] = *(const short8v*)(wtp + (((ph*18 + q)*2 + mt)*64 + l)*8);
    #pragma unroll
    for (int q = 0; q < 18; ++q) {
      int kt = ph*18 + q;
      int tap = kt >> 2;
      int ioff2 = ((kt & 3)*16 + lh*8) * 2;
#define DOCT(ACC, CTL) { \
      int col = (cth*4 + (CTL))*32 + lane31; \
      int tvB = (col < 200 ? col : 199) + 25*tap; \
      int ab = (tvB << 7) + (ioff2 ^ ((tvB & 7) << 4)); \
      short8v b = *(const short8v*)(ubuf + ab); \
      ACC = __builtin_amdgcn_mfma_f32_32x32x16_bf16(af[q], b, ACC, 0, 0, 0); }
      DOCT(acc0, 0) DOCT(acc1, 1) DOCT(acc2, 2) DOCT(acc3, 3)
#undef DOCT
    }
  }
  __syncthreads();

  // --- C-frags -> LDS [o][201] f32 ---
  float* tcl = (float*)ubuf;
  {
    int rowbase = mt*32 + 4*lh;
#define STCT(ACC, CTL) { \
    int col = (cth*4 + (CTL))*32 + lane31; \
    if (col < 201) { \
      _Pragma("unroll") \
      for (int rg = 0; rg < 16; ++rg) { \
        int o = rowbase + (rg & 3) + 8*(rg >> 2); \
        tcl[o*201 + col] = ACC[rg]; } } }
    STCT(acc0, 0) STCT(acc1, 1) STCT(acc2, 2) STCT(acc3, 3)
#undef STCT
  }
  __syncthreads();

  // --- bias + BN2 stats + bf16 store ([n][t][v][o]) ---
  {
    int o = tid & 63, ch = tid >> 6;
    float bto = bt[o];
    int lim = 7500 - t0*25; if (lim > 200) lim = 200;
    int wsbase = n*480000 + t0*1600 + o;
    float sm = 0.f, sq = 0.f;
    for (int q = 0; q < 50; ++q) {
      int tv = ch*50 + q;
      if (tv < lim) {
        float val = tcl[o*201 + tv] + bto;
        tco[wsbase + tv*64] = f2bf(val);
        sm += val; sq += val*val;
      }
    }
    atomicAdd(&s_sum[o], sm);
    atomicAdd(&s_sq[o], sq);
  }
  __syncthreads();
  if (tid < CB) {
    atomicAdd(&wstat[WS_SUM2 + tid], s_sum[tid]);
    atomicAdd(&wstat[WS_SQ2  + tid], s_sq[tid]);
  }
}

// ---------------- K5: out = relu(bn2(tc) + x), full f32 d_out ---------------
__global__ __launch_bounds__(256) void k5_final(
    const float* __restrict__ x, const float* __restrict__ ws,
    const unsigned short* __restrict__ tc, float* __restrict__ out)
{
  __shared__ float tl5[200*65];
  int tid = threadIdx.x;
  int t0 = blockIdx.x * 8;
  int n  = blockIdx.y;
  int lim = 7500 - t0*25; if (lim > 200) lim = 200;
  int base = n*480000 + t0*1600;
  for (int idx = tid; idx < 200*64; idx += 256) {
    int tv = idx >> 6, o = idx & 63;
    if (tv < lim)
      tl5[tv*65 + o] = bf2f(tc[base + idx]);
  }
  __syncthreads();
  int w = tid >> 6, lane = tid & 63;
  for (int ol = 0; ol < 16; ++ol) {
    int o = w*16 + ol;
    float sc = ws[WS_SC2 + o], sh = ws[WS_SH2 + o];
    size_t gb = (size_t)(n*64 + o)*7500 + t0*25;
    #pragma unroll
    for (int c2 = 0; c2 < 4; ++c2) {
      int tv = c2*64 + lane;
      if (tv < lim) {
        float val = fmaf(tl5[tv*65 + o], sc, sh) + x[gb + tv];
        out[gb + tv] = fmaxf(val, 0.f);
      }
    }
  }
}

extern "C" void kernel_launch(void* const* d_in, const int* in_sizes, int n_in,
                              void* d_out, int out_size, void* d_ws, size_t ws_size,
                              hipStream_t stream) {
  const float* x  = (const float*)d_in[0];
  const float* A  = (const float*)d_in[1];
  const float* PA = (const float*)d_in[2];
  const float* Wd = (const float*)d_in[3];
  const float* bd = (const float*)d_in[4];
  const float* g1 = (const float*)d_in[5];
  const float* b1 = (const float*)d_in[6];
  const float* Wt = (const float*)d_in[7];
  const float* bt = (const float*)d_in[8];
  const float* g2 = (const float*)d_in[9];
  const float* b2 = (const float*)d_in[10];

  float* ws = (float*)d_ws;
  unsigned short* zbuf = (unsigned short*)d_out;            // z' scratch
  unsigned short* xtb  = (unsigned short*)d_out + ZP_ELEMS; // xT scratch
  unsigned short* tc   = (unsigned short*)((char*)d_ws + WS_TC_BYTE);
  float* out = (float*)d_out;

  k0_prep<<<dim3(64), dim3(256), 0, stream>>>(A, PA, Wd, Wt, ws);
  k1_gcn<<<dim3(75, 64), dim3(512), 0, stream>>>(x, bd, ws, ws, zbuf, xtb);
  k_fin<<<dim3(1), dim3(64), 0, stream>>>(g1, b1, ws, 0);
  k3_mfma<<<dim3(38, 64), dim3(256), 0, stream>>>(zbuf, xtb, bt, ws, ws, tc);
  k_fin<<<dim3(1), dim3(64), 0, stream>>>(g2, b2, ws, 256);
  k5_final<<<dim3(38, 64), dim3(256), 0, stream>>>(x, ws, tc, out);
}